// Round 12
// baseline (804.416 us; speedup 1.0000x reference)
//
#include <hip/hip_runtime.h>

typedef unsigned short u16;
typedef unsigned int u32;
typedef unsigned long long u64;

#define E_TOT 202752   // B*N0*DEG = 32*1584*4
#define NMAX  50688    // B*N0
#define EPG   6336     // edges per graph = N0*DEG
#define HEADS 4
#define B_    32
#define MAXDEG 32      // Poisson(4) in-degree: P(>=32) ~ 1e-18/node — safe bucket

#define CDIV(a,b) (((a)+(b)-1)/(b))

// order-preserving float->uint map (monotonic); code 0 is below any real float's code
__device__ __forceinline__ u32 ford(float f) {
  u32 u = __float_as_uint(f);
  return (u & 0x80000000u) ? ~u : (u | 0x80000000u);
}
__device__ __forceinline__ float ford_inv(u32 u) {
  u32 b = (u & 0x80000000u) ? (u ^ 0x80000000u) : ~u;
  return __uint_as_float(b);
}

// DPP row-rotate (16-lane row) move; CTRL = 0x120 | n for row_ror:n
template <int CTRL>
__device__ __forceinline__ float dpp_mov(float x) {
  return __int_as_float(__builtin_amdgcn_mov_dpp(__float_as_int(x), CTRL, 0xF, 0xF, false));
}
// sum over each 16-lane row via VALU-pipe rotations (no DS pipe on the hot path)
__device__ __forceinline__ float row16_sum(float v) {
  v += dpp_mov<0x121>(v);   // row_ror:1
  v += dpp_mov<0x122>(v);   // row_ror:2
  v += dpp_mov<0x124>(v);   // row_ror:4
  v += dpp_mov<0x128>(v);   // row_ror:8
  return v;
}

__device__ __forceinline__ u64 shfl_xor_u64(u64 v, int mask) {
  int lo = __shfl_xor((int)(u32)(v & 0xFFFFFFFFu), mask, 64);
  int hi = __shfl_xor((int)(u32)(v >> 32), mask, 64);
  return ((u64)(u32)hi << 32) | (u32)lo;
}

// edge arrays + CSR for layer 0 in one pass (cnt+csr pre-zeroed by merged memset)
__global__ void k_edge_init_csr(const int* __restrict__ ei, int* __restrict__ src,
                                int* __restrict__ dst, int* __restrict__ em,
                                int* __restrict__ cnt, int* __restrict__ csr) {
  int e = blockIdx.x * blockDim.x + threadIdx.x;
  if (e >= E_TOT) return;
  int s = ei[e], d = ei[E_TOT + e];
  src[e] = s;
  dst[e] = d;
  em[e] = 1;
  int pos = atomicAdd(&cnt[d], 1);
  if (pos < MAXDEG) csr[d * MAXDEG + pos] = e;
}

// ---------- node transform, 16 nodes/block, transposed-LDS x, b128 broadcast reads ----
template <int FIN>
__global__ void k_transform_t(const float* __restrict__ hin,
                              const float* __restrict__ Wl, const float* __restrict__ bl,
                              const float* __restrict__ Wr, const float* __restrict__ br,
                              float* __restrict__ xl, float* __restrict__ xr) {
  __shared__ float xs[FIN][20];
  int n0 = blockIdx.x * 16, j = threadIdx.x;   // 256 threads
  for (int t = j; t < 16 * FIN; t += 256) {
    int nd = t >> (FIN == 32 ? 5 : 6), f = t & (FIN - 1);
    xs[f][nd] = hin[(size_t)(n0 + nd) * FIN + f];
  }
  __syncthreads();
  float al[16], ar[16];
  float blv = bl[j], brv = br[j];
#pragma unroll
  for (int t = 0; t < 16; ++t) { al[t] = blv; ar[t] = brv; }
  for (int i = 0; i < FIN; ++i) {
    float wl = Wl[i * 256 + j], wr = Wr[i * 256 + j];
    float4 x0 = *(const float4*)&xs[i][0];     // broadcast b128 reads
    float4 x1 = *(const float4*)&xs[i][4];
    float4 x2 = *(const float4*)&xs[i][8];
    float4 x3 = *(const float4*)&xs[i][12];
    al[0]  += x0.x * wl; ar[0]  += x0.x * wr;
    al[1]  += x0.y * wl; ar[1]  += x0.y * wr;
    al[2]  += x0.z * wl; ar[2]  += x0.z * wr;
    al[3]  += x0.w * wl; ar[3]  += x0.w * wr;
    al[4]  += x1.x * wl; ar[4]  += x1.x * wr;
    al[5]  += x1.y * wl; ar[5]  += x1.y * wr;
    al[6]  += x1.z * wl; ar[6]  += x1.z * wr;
    al[7]  += x1.w * wl; ar[7]  += x1.w * wr;
    al[8]  += x2.x * wl; ar[8]  += x2.x * wr;
    al[9]  += x2.y * wl; ar[9]  += x2.y * wr;
    al[10] += x2.z * wl; ar[10] += x2.z * wr;
    al[11] += x2.w * wl; ar[11] += x2.w * wr;
    al[12] += x3.x * wl; ar[12] += x3.x * wr;
    al[13] += x3.y * wl; ar[13] += x3.y * wr;
    al[14] += x3.z * wl; ar[14] += x3.z * wr;
    al[15] += x3.w * wl; ar[15] += x3.w * wr;
  }
#pragma unroll
  for (int t = 0; t < 16; ++t) {
    xl[(size_t)(n0 + t) * 256 + j] = al[t];
    xr[(size_t)(n0 + t) * 256 + j] = ar[t];
  }
}

// ---------- fused GATv2 — EXACT R6-verified version (67us L0, FETCH 78MB, WRITE 13MB,
// VALUBusy 48%, 56 VGPR). R10's depth-2 prefetch spilled (WRITE 13->37MB) — reverted.
__global__ void k_gat_fused(const int* __restrict__ srcv, const int* __restrict__ cnt,
                            const int* __restrict__ csr, const float* __restrict__ ea,
                            const float* __restrict__ We, const float* __restrict__ att,
                            const float* __restrict__ xl, const float* __restrict__ xr,
                            const float* __restrict__ bias, const float* __restrict__ pwv,
                            float* __restrict__ out, float* __restrict__ sc,
                            int n_per) {
  int b = blockIdx.x;
  int xcd = b & 7;
  int jj = b >> 3;                                 // 0..255 within XCD
  int g = xcd + 8 * (jj >> 6);                     // graph 0..31, g%8 == xcd
  int wv = ((jj & 63) << 2) + (threadIdx.x >> 6);  // wave-in-graph 0..255
  int lane = threadIdx.x & 63;
  int cg = lane & 15;
  int cb = (lane >> 4) * 64 + cg * 4;              // this lane's 4 channels
  int npw = CDIV(n_per, 256);
  int l0 = wv * npw, l1 = min(n_per, l0 + npw);
  if (l0 >= n_per) return;
  int n0 = g * n_per + l0, n1 = g * n_per + l1;
  // per-layer constants, hoisted once per wave
  float4 at4 = *(const float4*)(att + cb);
  float4 w0 = *(const float4*)(We + 0 * 256 + cb);
  float4 w1 = *(const float4*)(We + 1 * 256 + cb);
  float4 w2 = *(const float4*)(We + 2 * 256 + cb);
  float4 w3 = *(const float4*)(We + 3 * 256 + cb);
  float4 w4_ = *(const float4*)(We + 4 * 256 + cb);
  float4 w5 = *(const float4*)(We + 5 * 256 + cb);
  float4 w6 = *(const float4*)(We + 6 * 256 + cb);
  float4 w7 = *(const float4*)(We + 7 * 256 + cb);
  float4 bi4 = *(const float4*)(bias + cg * 4);
  float4 pw4 = *(const float4*)(pwv + cg * 4);
  float wn = pw4.x * pw4.x + pw4.y * pw4.y + pw4.z * pw4.z + pw4.w * pw4.w;
  wn += __shfl_xor(wn, 1, 64); wn += __shfl_xor(wn, 2, 64);
  wn += __shfl_xor(wn, 4, 64); wn += __shfl_xor(wn, 8, 64);
  float isq = 1.f / sqrtf(wn);

  // pipeline prologue: first node's metadata + xr row in flight
  int degc = cnt[n0];
  int e_c = (lane < MAXDEG) ? csr[n0 * MAXDEG + lane] : 0;
  int s_c = srcv[e_c];                            // garbage beyond deg: masked later
  float4 xdc = *(const float4*)(xr + (size_t)n0 * 256 + cb);

  for (int n = n0; n < n1; ++n) {
    // issue NEXT node's loads first: they drain while we compute this node
    int degn = 0, e_n = 0, s_n = 0;
    float4 xdn = xdc;
    if (n + 1 < n1) {
      degn = cnt[n + 1];
      e_n = (lane < MAXDEG) ? csr[(n + 1) * MAXDEG + lane] : 0;
      s_n = srcv[e_n];
      xdn = *(const float4*)(xr + (size_t)(n + 1) * 256 + cb);
    }
    int deg = min(degc, MAXDEG);
    int e_l = e_c, s_l = s_c;
    float4 xd4 = xdc;
    float m = -INFINITY, l = 0.f;
    float ox = 0.f, oy = 0.f, oz = 0.f, ow = 0.f;
    for (int i0 = 0; i0 < deg; i0 += 4) {
      int c0 = deg - i0; if (c0 > 4) c0 = 4;       // wave-uniform
      float4 xs[4], a0[4], a1[4];
#pragma unroll
      for (int j = 0; j < 4; ++j) {
        int idx = (j < c0) ? (i0 + j) : i0;        // clamp to a safe slot (uniform)
        int e = __builtin_amdgcn_readlane(e_l, idx);   // VALU->SGPR broadcast
        int s = __builtin_amdgcn_readlane(s_l, idx);
        xs[j] = *(const float4*)(xl + (size_t)s * 256 + cb);   // independent, in flight
        a0[j] = *(const float4*)(ea + (size_t)e * 8);
        a1[j] = *(const float4*)(ea + (size_t)e * 8 + 4);
      }
      // --- logits for the whole chunk, fully independent across j ---
      float v[4];
#pragma unroll
      for (int j = 0; j < 4; ++j) {
        if (j < c0) {
          float e0 = a0[j].x * w0.x + a0[j].y * w1.x + a0[j].z * w2.x + a0[j].w * w3.x
                   + a1[j].x * w4_.x + a1[j].y * w5.x + a1[j].z * w6.x + a1[j].w * w7.x;
          float e1 = a0[j].x * w0.y + a0[j].y * w1.y + a0[j].z * w2.y + a0[j].w * w3.y
                   + a1[j].x * w4_.y + a1[j].y * w5.y + a1[j].z * w6.y + a1[j].w * w7.y;
          float e2 = a0[j].x * w0.z + a0[j].y * w1.z + a0[j].z * w2.z + a0[j].w * w3.z
                   + a1[j].x * w4_.z + a1[j].y * w5.z + a1[j].z * w6.z + a1[j].w * w7.z;
          float e3 = a0[j].x * w0.w + a0[j].y * w1.w + a0[j].z * w2.w + a0[j].w * w3.w
                   + a1[j].x * w4_.w + a1[j].y * w5.w + a1[j].z * w6.w + a1[j].w * w7.w;
          float m0 = xs[j].x + xd4.x + e0; m0 = (m0 >= 0.f) ? m0 : 0.2f * m0;  // leaky
          float m1 = xs[j].y + xd4.y + e1; m1 = (m1 >= 0.f) ? m1 : 0.2f * m1;
          float m2 = xs[j].z + xd4.z + e2; m2 = (m2 >= 0.f) ? m2 : 0.2f * m2;
          float m3 = xs[j].w + xd4.w + e3; m3 = (m3 >= 0.f) ? m3 : 0.2f * m3;
          float d = at4.x * m0 + at4.y * m1 + at4.z * m2 + at4.w * m3;
          v[j] = row16_sum(d);           // 4 independent DPP chains interleave on VALU
        } else {
          v[j] = -INFINITY;              // pad slot: p=exp(-inf-nm)=0, no contribution
        }
      }
      // --- ONE max + rescale for the whole chunk ---
      float vm = fmaxf(fmaxf(v[0], v[1]), fmaxf(v[2], v[3]));
      float nm = fmaxf(m, vm);
      float scale = __expf(m - nm);      // first chunk: m=-inf -> scale=0
      float p0 = __expf(v[0] - nm), p1 = __expf(v[1] - nm);
      float p2 = __expf(v[2] - nm), p3 = __expf(v[3] - nm);
      ox = ox * scale + ((p0 * xs[0].x + p1 * xs[1].x) + (p2 * xs[2].x + p3 * xs[3].x));
      oy = oy * scale + ((p0 * xs[0].y + p1 * xs[1].y) + (p2 * xs[2].y + p3 * xs[3].y));
      oz = oz * scale + ((p0 * xs[0].z + p1 * xs[1].z) + (p2 * xs[2].z + p3 * xs[3].z));
      ow = ow * scale + ((p0 * xs[0].w + p1 * xs[1].w) + (p2 * xs[2].w + p3 * xs[3].w));
      l = l * scale + ((p0 + p1) + (p2 + p3));
      m = nm;
    }
    // per-head y = O/den, then 0.25 * head-sum  (deg==0 -> l=0 -> y=0, matches ref)
    float inv = 0.25f / fmaxf(l, 1e-16f);
    float r0 = ox * inv, r1 = oy * inv, r2 = oz * inv, r3 = ow * inv;
    r0 += __shfl_xor(r0, 16, 64); r0 += __shfl_xor(r0, 32, 64);
    r1 += __shfl_xor(r1, 16, 64); r1 += __shfl_xor(r1, 32, 64);
    r2 += __shfl_xor(r2, 16, 64); r2 += __shfl_xor(r2, 32, 64);
    r3 += __shfl_xor(r3, 16, 64); r3 += __shfl_xor(r3, 32, 64);
    float rr0 = fmaxf(r0 + bi4.x, 0.f), rr1 = fmaxf(r1 + bi4.y, 0.f);
    float rr2 = fmaxf(r2 + bi4.z, 0.f), rr3 = fmaxf(r3 + bi4.w, 0.f);
    if (lane < 16) *(float4*)(out + (size_t)n * 64 + cg * 4) = float4{rr0, rr1, rr2, rr3};
    // topk score: s = tanh(h.w / ||w||)
    float dot = rr0 * pw4.x + rr1 * pw4.y + rr2 * pw4.z + rr3 * pw4.w;
    dot += __shfl_xor(dot, 1, 64);
    dot += __shfl_xor(dot, 2, 64);
    dot += __shfl_xor(dot, 4, 64);
    dot += __shfl_xor(dot, 8, 64);
    if (lane == 0) sc[n] = tanhf(dot * isq);
    // rotate pipeline registers
    degc = degn; e_c = e_n; s_c = s_n; xdc = xdn;
  }
}

// ---------- k_pool: topk sort + WIDE gather/readout/remap in ONE dispatch ----------
// grid (32, 16) x 1024 threads = 512 blocks = 8192 waves (exactly co-resident).
// Block (b,0): R6 bitonic sort for graph b -> perm/new_id -> device-scope flag release.
// Blocks (b,1..15): spin on flag (safe: all blocks co-resident; role-0 blocks dispatch
// first), then gather+readout (15 blocks/graph = 480 wide) and edge remap.
// Width preserved (R10's 32-block fusion regressed 40us); saves 1 dispatch boundary/layer.
__global__ __launch_bounds__(1024) void k_pool(
    const float* __restrict__ s, const float* __restrict__ hin, float* __restrict__ hout,
    float* __restrict__ rsum, u32* __restrict__ rmaxI,
    int* __restrict__ src, int* __restrict__ dst, int* __restrict__ em,
    int* __restrict__ cnt, int* __restrict__ csr,
    int* __restrict__ perm, int* __restrict__ new_id, int* __restrict__ flag,
    int n_per, int k, int do_remap) {
  __shared__ u64 kv[2048];             // 16 KB; reused as ps/pm by worker roles
  int b = blockIdx.x, role = blockIdx.y, t = threadIdx.x;
  int base = b * n_per;

  if (role == 0) {
    // ---- R6-verified hybrid bitonic sort (identical math) ----
    for (int i = t; i < n_per; i += 1024) new_id[base + i] = -1;
    for (int i = t; i < k; i += 1024) cnt[b * k + i] = 0;   // next layer's CSR counters
    u64 e0, e1;
    {
      u32 sk0 = (t < n_per) ? ford(s[base + t]) : 0u;           // pad key 0: below all
      int i1 = t + 1024;
      u32 sk1 = (i1 < n_per) ? ford(s[base + i1]) : 0u;
      e0 = ((u64)sk0 << 32) | (u32)(0xFFFFFFFFu - (u32)t);      // tie -> lower idx first
      e1 = ((u64)sk1 << 32) | (u32)(0xFFFFFFFFu - (u32)i1);
    }
    for (int kk = 2; kk <= 2048; kk <<= 1) {
      int j = kk >> 1;
      if (j == 1024) {                   // partner is the other register: local
        u64 mx = e0 > e1 ? e0 : e1;
        u64 mn = e0 > e1 ? e1 : e0;
        e0 = mx; e1 = mn;
        j >>= 1;
      }
      for (; j >= 64; j >>= 1) {         // cross-wave: LDS exchange
        __syncthreads();                 // prior pass's reads complete before overwrite
        kv[t] = e0; kv[t + 1024] = e1;
        __syncthreads();
        u64 p0 = kv[t ^ j], p1 = kv[(t + 1024) ^ j];
        int i1 = t + 1024;
        bool km0 = (((t  & kk) == 0) == ((t  & j) == 0));
        bool km1 = (((i1 & kk) == 0) == ((i1 & j) == 0));
        e0 = km0 ? (e0 > p0 ? e0 : p0) : (e0 < p0 ? e0 : p0);
        e1 = km1 ? (e1 > p1 ? e1 : p1) : (e1 < p1 ? e1 : p1);
      }
      for (; j >= 1; j >>= 1) {          // intra-wave: shuffle exchange, no barriers
        u64 p0 = shfl_xor_u64(e0, j);
        u64 p1 = shfl_xor_u64(e1, j);
        int i1 = t + 1024;
        bool km0 = (((t  & kk) == 0) == ((t  & j) == 0));
        bool km1 = (((i1 & kk) == 0) == ((i1 & j) == 0));
        e0 = km0 ? (e0 > p0 ? e0 : p0) : (e0 < p0 ? e0 : p0);
        e1 = km1 ? (e1 > p1 ? e1 : p1) : (e1 < p1 ? e1 : p1);
      }
    }
    if (t < k) {
      int old0 = (int)(0xFFFFFFFFu - (u32)(e0 & 0xFFFFFFFFu));
      perm[b * k + t] = base + old0;
      new_id[base + old0] = b * k + t;
    }
    int r1 = t + 1024;
    if (r1 < k) {
      int old1 = (int)(0xFFFFFFFFu - (u32)(e1 & 0xFFFFFFFFu));
      perm[b * k + r1] = base + old1;
      new_id[base + old1] = b * k + r1;
    }
    // release: all perm/new_id/cnt writes visible before flag flips
    __syncthreads();
    __threadfence();
    if (t == 0) atomicExch(&flag[b], 1);
    return;
  }

  // ---- worker roles 1..15: wait for graph b's sort ----
  if (t == 0) {
    while (atomicAdd(&flag[b], 0) == 0) { __builtin_amdgcn_s_sleep(8); }
  }
  __syncthreads();
  __threadfence();                       // acquire: invalidate caches before reading perm

  float* ps = (float*)kv;                // LDS reuse (16KB >= 8KB)
  float* pm = ps + 1024;
  int slice = role - 1;                  // 0..14
  int per = CDIV(k, 15);
  int i0 = slice * per, i1e = min(k, i0 + per);
  {
    int c = t & 63;
    float acc = 0.f, mx = -INFINITY;
    for (int i = i0 + (t >> 6); i < i1e; i += 16) {   // 16 nodes per pass
      int gidx = perm[b * k + i];
      float v = hin[(size_t)gidx * 64 + c] * s[gidx];
      hout[((size_t)b * k + i) * 64 + c] = v;
      acc += v;
      mx = fmaxf(mx, v);
    }
    ps[t] = acc;
    pm[t] = mx;
  }
  __syncthreads();
  if (t < 64) {
    float s4 = 0.f, m4 = -INFINITY;
#pragma unroll
    for (int j = 0; j < 16; ++j) {
      s4 += ps[t + j * 64];
      m4 = fmaxf(m4, pm[t + j * 64]);
    }
    atomicAdd(&rsum[b * 64 + t], s4);
    atomicMax(&rmaxI[b * 64 + t], ford(m4));
  }

  if (do_remap) {
    for (int e = b * EPG + slice * 1024 + t; e < (b + 1) * EPG; e += 15 * 1024) {
      int ns = new_id[src[e]], nd = new_id[dst[e]];
      int mm = em[e] && ns >= 0 && nd >= 0;
      src[e] = mm ? ns : 0;
      dst[e] = mm ? nd : 0;
      em[e] = mm;
      if (mm) {
        int pos = atomicAdd(&cnt[nd], 1);
        if (pos < MAXDEG) csr[nd * MAXDEG + pos] = e;
      }
    }
  }
}

// MLP with readout finalization folded in: reads [rsum|rmaxI] x 3 layers directly
__global__ void k_mlp(const char* __restrict__ rblk,
                      const float* __restrict__ W1, const float* __restrict__ b1,
                      const float* __restrict__ W2, const float* __restrict__ b2,
                      const float* __restrict__ W3, const float* __restrict__ b3,
                      float* __restrict__ out) {
  __shared__ float v0[128], v1[64], v2[64], lgts[16];
  int b = blockIdx.x, t = threadIdx.x;   // 64 threads
  const float* rs0 = (const float*)rblk;
  const u32*   rm0 = (const u32*)(rblk + 32 * 64 * 4);
  const float* rs1 = (const float*)(rblk + 32 * 128 * 4);
  const u32*   rm1 = (const u32*)(rblk + 32 * 128 * 4 + 32 * 64 * 4);
  const float* rs2 = (const float*)(rblk + 2 * 32 * 128 * 4);
  const u32*   rm2 = (const u32*)(rblk + 2 * 32 * 128 * 4 + 32 * 64 * 4);
  v0[t] = rs0[b * 64 + t] / 1268.f + rs1[b * 64 + t] / 1015.f + rs2[b * 64 + t] / 812.f;
  v0[64 + t] = ford_inv(rm0[b * 64 + t]) + ford_inv(rm1[b * 64 + t]) + ford_inv(rm2[b * 64 + t]);
  __syncthreads();
  float a = b1[t];
  for (int i = 0; i < 128; ++i) a += v0[i] * W1[i * 64 + t];
  v1[t] = fmaxf(a, 0.f);
  __syncthreads();
  a = b2[t];
  for (int i = 0; i < 64; ++i) a += v1[i] * W2[i * 64 + t];
  v2[t] = fmaxf(a, 0.f);
  __syncthreads();
  if (t < 16) {
    a = b3[t];
    for (int i = 0; i < 64; ++i) a += v2[i] * W3[i * 16 + t];
    lgts[t] = a;
  }
  __syncthreads();
  if (t == 0) {
    float m = lgts[0];
    for (int j = 1; j < 16; ++j) m = fmaxf(m, lgts[j]);
    float ex[16], sum = 0.f;
    for (int j = 0; j < 16; ++j) { ex[j] = expf(lgts[j] - m); sum += ex[j]; }
    for (int j = 0; j < 16; ++j) out[b * 16 + j] = ex[j] / sum;
  }
}

extern "C" void kernel_launch(void* const* d_in, const int* in_sizes, int n_in,
                              void* d_out, int out_size, void* d_ws, size_t ws_size,
                              hipStream_t stream) {
  (void)in_sizes; (void)n_in; (void)out_size; (void)ws_size;
  const float* x  = (const float*)d_in[0];      // [NMAX, 32] f32
  const float* ea = (const float*)d_in[1];      // [E, 8]     f32
  const int*   ei = (const int*)d_in[2];        // [2, E]

  const float *gWl[3], *gbl[3], *gWr[3], *gbr[3], *gWe[3], *gatt[3], *gb[3], *pw[3];
  for (int l = 0; l < 3; ++l) {
    int p0 = 4 + 7 * l;
    gWl[l]  = (const float*)d_in[p0 + 0];
    gbl[l]  = (const float*)d_in[p0 + 1];
    gWr[l]  = (const float*)d_in[p0 + 2];
    gbr[l]  = (const float*)d_in[p0 + 3];
    gWe[l]  = (const float*)d_in[p0 + 4];
    gatt[l] = (const float*)d_in[p0 + 5];
    gb[l]   = (const float*)d_in[p0 + 6];
    pw[l]   = (const float*)d_in[25 + l];
  }
  const float* fc1W = (const float*)d_in[28];
  const float* fc1b = (const float*)d_in[29];
  const float* fc2W = (const float*)d_in[30];
  const float* fc2b = (const float*)d_in[31];
  const float* fc3W = (const float*)d_in[32];
  const float* fc3b = (const float*)d_in[33];

  // ---- workspace carve. cnt|rblk|csr|flags CONTIGUOUS (sizes %256==0): ONE memset ----
  char* w = (char*)d_ws;
  size_t off = 0;
  auto alloc = [&](size_t bytes) -> void* {
    void* p = w + off;
    off += (bytes + 255) & ~(size_t)255;
    return p;
  };
  float* hbuf = (float*)alloc((size_t)B_ * 1268 * 64 * 4); // pooled features (max K1)
  float* xl   = (float*)alloc((size_t)NMAX * 256 * 4);     // source transform [N,256]
  float* xr   = (float*)alloc((size_t)NMAX * 256 * 4);     // target transform [N,256]
  float* nacc = (float*)alloc((size_t)NMAX * 64 * 4);      // fused GAT output (pre-pool)
  int*   cnt  = (int*)alloc((size_t)NMAX * 4);             // CSR degree counters
  char*  rblk = (char*)alloc(3 * 32 * 128 * 4);            // per-layer [rsum][rmaxI] x3
  int*   csr  = (int*)alloc((size_t)NMAX * MAXDEG * 4);
  int*   flags= (int*)alloc(3 * 32 * 4);                   // per-layer sort-done flags
  float* sbuf = (float*)alloc((size_t)NMAX * 4);
  int* src    = (int*)alloc((size_t)E_TOT * 4);
  int* dst    = (int*)alloc((size_t)E_TOT * 4);
  int* em     = (int*)alloc((size_t)E_TOT * 4);
  int* new_id = (int*)alloc((size_t)NMAX * 4);
  int* perm   = (int*)alloc((size_t)32 * 1268 * 4);

  // one-time zero of cnt + rblk + csr + flags (csr zero => every slot an in-bounds
  // edge id forever, enabling k_gat_fused's unconditional csr/srcv prefetch)
  size_t zbytes = (size_t)NMAX * 4 + 3 * 32 * 128 * 4 + (size_t)NMAX * MAXDEG * 4
                + 256 /*flags rounded*/;
  hipMemsetAsync(cnt, 0, zbytes, stream);
  k_edge_init_csr<<<CDIV(E_TOT, 256), 256, 0, stream>>>(ei, src, dst, em, cnt, csr);

  const int Ns[3]    = {50688, 40576, 32480};   // B*N0, B*K1, B*K2 (all %16==0)
  const int npers[3] = {1584, 1268, 1015};
  const int ks[3]    = {1268, 1015, 812};
  const int GAT_BLOCKS = 2048;                  // 8 XCD x 4 graphs x 64 blocks

  for (int l = 0; l < 3; ++l) {
    int N = Ns[l];
    const float* hin = (l == 0) ? x : hbuf;
    float* rsum = (float*)(rblk + l * 32 * 128 * 4);
    u32* rmaxI  = (u32*)(rblk + l * 32 * 128 * 4 + 32 * 64 * 4);
    if (l == 0)
      k_transform_t<32><<<N / 16, 256, 0, stream>>>(hin, gWl[l], gbl[l], gWr[l], gbr[l], xl, xr);
    else
      k_transform_t<64><<<N / 16, 256, 0, stream>>>(hin, gWl[l], gbl[l], gWr[l], gbr[l], xl, xr);
    k_gat_fused<<<GAT_BLOCKS, 256, 0, stream>>>(src, cnt, csr, ea, gWe[l], gatt[l],
                                                xl, xr, gb[l], pw[l], nacc, sbuf, npers[l]);
    k_pool<<<dim3(32, 16), 1024, 0, stream>>>(sbuf, nacc, hbuf, rsum, rmaxI,
                                              src, dst, em, cnt, csr,
                                              perm, new_id, flags + l * 32,
                                              npers[l], ks[l], (l < 2) ? 1 : 0);
  }
  k_mlp<<<32, 64, 0, stream>>>(rblk, fc1W, fc1b, fc2W, fc2b, fc3W, fc3b, (float*)d_out);
}

// Round 14
// 477.803 us; speedup vs baseline: 1.6836x; 1.6836x over previous
//
#include <hip/hip_runtime.h>

typedef unsigned short u16;
typedef unsigned int u32;
typedef unsigned long long u64;

#define E_TOT 202752   // B*N0*DEG = 32*1584*4
#define NMAX  50688    // B*N0
#define HEADS 4
#define B_    32
#define MAXDEG 32      // Poisson(4) in-degree: P(>=32) ~ 1e-18/node — safe bucket
#define REMAP_Y 25     // CDIV(E_TOT, 32*256)

#define CDIV(a,b) (((a)+(b)-1)/(b))

// order-preserving float->uint map (monotonic); code 0 is below any real float's code
__device__ __forceinline__ u32 ford(float f) {
  u32 u = __float_as_uint(f);
  return (u & 0x80000000u) ? ~u : (u | 0x80000000u);
}
__device__ __forceinline__ float ford_inv(u32 u) {
  u32 b = (u & 0x80000000u) ? (u ^ 0x80000000u) : ~u;
  return __uint_as_float(b);
}

// DPP row-rotate (16-lane row) move; CTRL = 0x120 | n for row_ror:n
template <int CTRL>
__device__ __forceinline__ float dpp_mov(float x) {
  return __int_as_float(__builtin_amdgcn_mov_dpp(__float_as_int(x), CTRL, 0xF, 0xF, false));
}
// sum over each 16-lane row via VALU-pipe rotations (no DS pipe on the hot path)
__device__ __forceinline__ float row16_sum(float v) {
  v += dpp_mov<0x121>(v);   // row_ror:1
  v += dpp_mov<0x122>(v);   // row_ror:2
  v += dpp_mov<0x124>(v);   // row_ror:4
  v += dpp_mov<0x128>(v);   // row_ror:8
  return v;
}

__device__ __forceinline__ u64 shfl_xor_u64(u64 v, int mask) {
  int lo = __shfl_xor((int)(u32)(v & 0xFFFFFFFFu), mask, 64);
  int hi = __shfl_xor((int)(u32)(v >> 32), mask, 64);
  return ((u64)(u32)hi << 32) | (u32)lo;
}

// edge arrays + CSR for layer 0 in one pass (cnt+csr pre-zeroed by merged memset)
__global__ void k_edge_init_csr(const int* __restrict__ ei, int* __restrict__ src,
                                int* __restrict__ dst, int* __restrict__ em,
                                int* __restrict__ cnt, int* __restrict__ csr) {
  int e = blockIdx.x * blockDim.x + threadIdx.x;
  if (e >= E_TOT) return;
  int s = ei[e], d = ei[E_TOT + e];
  src[e] = s;
  dst[e] = d;
  em[e] = 1;
  int pos = atomicAdd(&cnt[d], 1);
  if (pos < MAXDEG) csr[d * MAXDEG + pos] = e;
}

// ---------- node transform, 16 nodes/block, transposed-LDS x, b128 broadcast reads ----
template <int FIN>
__global__ void k_transform_t(const float* __restrict__ hin,
                              const float* __restrict__ Wl, const float* __restrict__ bl,
                              const float* __restrict__ Wr, const float* __restrict__ br,
                              float* __restrict__ xl, float* __restrict__ xr) {
  __shared__ float xs[FIN][20];
  int n0 = blockIdx.x * 16, j = threadIdx.x;   // 256 threads
  for (int t = j; t < 16 * FIN; t += 256) {
    int nd = t >> (FIN == 32 ? 5 : 6), f = t & (FIN - 1);
    xs[f][nd] = hin[(size_t)(n0 + nd) * FIN + f];
  }
  __syncthreads();
  float al[16], ar[16];
  float blv = bl[j], brv = br[j];
#pragma unroll
  for (int t = 0; t < 16; ++t) { al[t] = blv; ar[t] = brv; }
  for (int i = 0; i < FIN; ++i) {
    float wl = Wl[i * 256 + j], wr = Wr[i * 256 + j];
    float4 x0 = *(const float4*)&xs[i][0];     // broadcast b128 reads
    float4 x1 = *(const float4*)&xs[i][4];
    float4 x2 = *(const float4*)&xs[i][8];
    float4 x3 = *(const float4*)&xs[i][12];
    al[0]  += x0.x * wl; ar[0]  += x0.x * wr;
    al[1]  += x0.y * wl; ar[1]  += x0.y * wr;
    al[2]  += x0.z * wl; ar[2]  += x0.z * wr;
    al[3]  += x0.w * wl; ar[3]  += x0.w * wr;
    al[4]  += x1.x * wl; ar[4]  += x1.x * wr;
    al[5]  += x1.y * wl; ar[5]  += x1.y * wr;
    al[6]  += x1.z * wl; ar[6]  += x1.z * wr;
    al[7]  += x1.w * wl; ar[7]  += x1.w * wr;
    al[8]  += x2.x * wl; ar[8]  += x2.x * wr;
    al[9]  += x2.y * wl; ar[9]  += x2.y * wr;
    al[10] += x2.z * wl; ar[10] += x2.z * wr;
    al[11] += x2.w * wl; ar[11] += x2.w * wr;
    al[12] += x3.x * wl; ar[12] += x3.x * wr;
    al[13] += x3.y * wl; ar[13] += x3.y * wr;
    al[14] += x3.z * wl; ar[14] += x3.z * wr;
    al[15] += x3.w * wl; ar[15] += x3.w * wr;
  }
#pragma unroll
  for (int t = 0; t < 16; ++t) {
    xl[(size_t)(n0 + t) * 256 + j] = al[t];
    xr[(size_t)(n0 + t) * 256 + j] = ar[t];
  }
}

// ---------- fused GATv2 — EXACT R6-verified version (67us L0, FETCH 78MB, WRITE 13MB,
// VALUBusy 48%, 56 VGPR). Do not touch: R11 prefetch spilled, R12 spin-pool died.
__global__ void k_gat_fused(const int* __restrict__ srcv, const int* __restrict__ cnt,
                            const int* __restrict__ csr, const float* __restrict__ ea,
                            const float* __restrict__ We, const float* __restrict__ att,
                            const float* __restrict__ xl, const float* __restrict__ xr,
                            const float* __restrict__ bias, const float* __restrict__ pwv,
                            float* __restrict__ out, float* __restrict__ sc,
                            int n_per) {
  int b = blockIdx.x;
  int xcd = b & 7;
  int jj = b >> 3;                                 // 0..255 within XCD
  int g = xcd + 8 * (jj >> 6);                     // graph 0..31, g%8 == xcd
  int wv = ((jj & 63) << 2) + (threadIdx.x >> 6);  // wave-in-graph 0..255
  int lane = threadIdx.x & 63;
  int cg = lane & 15;
  int cb = (lane >> 4) * 64 + cg * 4;              // this lane's 4 channels
  int npw = CDIV(n_per, 256);
  int l0 = wv * npw, l1 = min(n_per, l0 + npw);
  if (l0 >= n_per) return;
  int n0 = g * n_per + l0, n1 = g * n_per + l1;
  // per-layer constants, hoisted once per wave
  float4 at4 = *(const float4*)(att + cb);
  float4 w0 = *(const float4*)(We + 0 * 256 + cb);
  float4 w1 = *(const float4*)(We + 1 * 256 + cb);
  float4 w2 = *(const float4*)(We + 2 * 256 + cb);
  float4 w3 = *(const float4*)(We + 3 * 256 + cb);
  float4 w4_ = *(const float4*)(We + 4 * 256 + cb);
  float4 w5 = *(const float4*)(We + 5 * 256 + cb);
  float4 w6 = *(const float4*)(We + 6 * 256 + cb);
  float4 w7 = *(const float4*)(We + 7 * 256 + cb);
  float4 bi4 = *(const float4*)(bias + cg * 4);
  float4 pw4 = *(const float4*)(pwv + cg * 4);
  float wn = pw4.x * pw4.x + pw4.y * pw4.y + pw4.z * pw4.z + pw4.w * pw4.w;
  wn += __shfl_xor(wn, 1, 64); wn += __shfl_xor(wn, 2, 64);
  wn += __shfl_xor(wn, 4, 64); wn += __shfl_xor(wn, 8, 64);
  float isq = 1.f / sqrtf(wn);

  // pipeline prologue: first node's metadata + xr row in flight
  int degc = cnt[n0];
  int e_c = (lane < MAXDEG) ? csr[n0 * MAXDEG + lane] : 0;
  int s_c = srcv[e_c];                            // garbage beyond deg: masked later
  float4 xdc = *(const float4*)(xr + (size_t)n0 * 256 + cb);

  for (int n = n0; n < n1; ++n) {
    // issue NEXT node's loads first: they drain while we compute this node
    int degn = 0, e_n = 0, s_n = 0;
    float4 xdn = xdc;
    if (n + 1 < n1) {
      degn = cnt[n + 1];
      e_n = (lane < MAXDEG) ? csr[(n + 1) * MAXDEG + lane] : 0;
      s_n = srcv[e_n];
      xdn = *(const float4*)(xr + (size_t)(n + 1) * 256 + cb);
    }
    int deg = min(degc, MAXDEG);
    int e_l = e_c, s_l = s_c;
    float4 xd4 = xdc;
    float m = -INFINITY, l = 0.f;
    float ox = 0.f, oy = 0.f, oz = 0.f, ow = 0.f;
    for (int i0 = 0; i0 < deg; i0 += 4) {
      int c0 = deg - i0; if (c0 > 4) c0 = 4;       // wave-uniform
      float4 xs[4], a0[4], a1[4];
#pragma unroll
      for (int j = 0; j < 4; ++j) {
        int idx = (j < c0) ? (i0 + j) : i0;        // clamp to a safe slot (uniform)
        int e = __builtin_amdgcn_readlane(e_l, idx);   // VALU->SGPR broadcast
        int s = __builtin_amdgcn_readlane(s_l, idx);
        xs[j] = *(const float4*)(xl + (size_t)s * 256 + cb);   // independent, in flight
        a0[j] = *(const float4*)(ea + (size_t)e * 8);
        a1[j] = *(const float4*)(ea + (size_t)e * 8 + 4);
      }
      // --- logits for the whole chunk, fully independent across j ---
      float v[4];
#pragma unroll
      for (int j = 0; j < 4; ++j) {
        if (j < c0) {
          float e0 = a0[j].x * w0.x + a0[j].y * w1.x + a0[j].z * w2.x + a0[j].w * w3.x
                   + a1[j].x * w4_.x + a1[j].y * w5.x + a1[j].z * w6.x + a1[j].w * w7.x;
          float e1 = a0[j].x * w0.y + a0[j].y * w1.y + a0[j].z * w2.y + a0[j].w * w3.y
                   + a1[j].x * w4_.y + a1[j].y * w5.y + a1[j].z * w6.y + a1[j].w * w7.y;
          float e2 = a0[j].x * w0.z + a0[j].y * w1.z + a0[j].z * w2.z + a0[j].w * w3.z
                   + a1[j].x * w4_.z + a1[j].y * w5.z + a1[j].z * w6.z + a1[j].w * w7.z;
          float e3 = a0[j].x * w0.w + a0[j].y * w1.w + a0[j].z * w2.w + a0[j].w * w3.w
                   + a1[j].x * w4_.w + a1[j].y * w5.w + a1[j].z * w6.w + a1[j].w * w7.w;
          float m0 = xs[j].x + xd4.x + e0; m0 = (m0 >= 0.f) ? m0 : 0.2f * m0;  // leaky
          float m1 = xs[j].y + xd4.y + e1; m1 = (m1 >= 0.f) ? m1 : 0.2f * m1;
          float m2 = xs[j].z + xd4.z + e2; m2 = (m2 >= 0.f) ? m2 : 0.2f * m2;
          float m3 = xs[j].w + xd4.w + e3; m3 = (m3 >= 0.f) ? m3 : 0.2f * m3;
          float d = at4.x * m0 + at4.y * m1 + at4.z * m2 + at4.w * m3;
          v[j] = row16_sum(d);           // 4 independent DPP chains interleave on VALU
        } else {
          v[j] = -INFINITY;              // pad slot: p=exp(-inf-nm)=0, no contribution
        }
      }
      // --- ONE max + rescale for the whole chunk ---
      float vm = fmaxf(fmaxf(v[0], v[1]), fmaxf(v[2], v[3]));
      float nm = fmaxf(m, vm);
      float scale = __expf(m - nm);      // first chunk: m=-inf -> scale=0
      float p0 = __expf(v[0] - nm), p1 = __expf(v[1] - nm);
      float p2 = __expf(v[2] - nm), p3 = __expf(v[3] - nm);
      ox = ox * scale + ((p0 * xs[0].x + p1 * xs[1].x) + (p2 * xs[2].x + p3 * xs[3].x));
      oy = oy * scale + ((p0 * xs[0].y + p1 * xs[1].y) + (p2 * xs[2].y + p3 * xs[3].y));
      oz = oz * scale + ((p0 * xs[0].z + p1 * xs[1].z) + (p2 * xs[2].z + p3 * xs[3].z));
      ow = ow * scale + ((p0 * xs[0].w + p1 * xs[1].w) + (p2 * xs[2].w + p3 * xs[3].w));
      l = l * scale + ((p0 + p1) + (p2 + p3));
      m = nm;
    }
    // per-head y = O/den, then 0.25 * head-sum  (deg==0 -> l=0 -> y=0, matches ref)
    float inv = 0.25f / fmaxf(l, 1e-16f);
    float r0 = ox * inv, r1 = oy * inv, r2 = oz * inv, r3 = ow * inv;
    r0 += __shfl_xor(r0, 16, 64); r0 += __shfl_xor(r0, 32, 64);
    r1 += __shfl_xor(r1, 16, 64); r1 += __shfl_xor(r1, 32, 64);
    r2 += __shfl_xor(r2, 16, 64); r2 += __shfl_xor(r2, 32, 64);
    r3 += __shfl_xor(r3, 16, 64); r3 += __shfl_xor(r3, 32, 64);
    float rr0 = fmaxf(r0 + bi4.x, 0.f), rr1 = fmaxf(r1 + bi4.y, 0.f);
    float rr2 = fmaxf(r2 + bi4.z, 0.f), rr3 = fmaxf(r3 + bi4.w, 0.f);
    if (lane < 16) *(float4*)(out + (size_t)n * 64 + cg * 4) = float4{rr0, rr1, rr2, rr3};
    // topk score: s = tanh(h.w / ||w||)
    float dot = rr0 * pw4.x + rr1 * pw4.y + rr2 * pw4.z + rr3 * pw4.w;
    dot += __shfl_xor(dot, 1, 64);
    dot += __shfl_xor(dot, 2, 64);
    dot += __shfl_xor(dot, 4, 64);
    dot += __shfl_xor(dot, 8, 64);
    if (lane == 0) sc[n] = tanhf(dot * isq);
    // rotate pipeline registers
    degc = degn; e_c = e_n; s_c = s_n; xdc = xdn;
  }
}

// stable descending top-k per graph — u64 keys (ford(score)<<32 | ~idx).
// Hybrid bitonic over 2048 elements, 2 elements/thread in registers (measured R6).
// Also zeroes cnt[0, B*k) for the next layer (replaces a hipMemsetAsync).
__global__ __launch_bounds__(1024) void k_topk(const float* __restrict__ s, int n_per,
                                               int k,
                                               int* __restrict__ perm, int* __restrict__ new_id,
                                               int* __restrict__ cnt) {
  __shared__ u64 kv[2048];
  int b = blockIdx.x, t = threadIdx.x;
  int base = b * n_per;
  for (int i = t; i < n_per; i += 1024) new_id[base + i] = -1;
  for (int i = t; i < k; i += 1024) cnt[b * k + i] = 0;   // next layer's CSR counters

  u64 e0, e1;
  {
    u32 sk0 = (t < n_per) ? ford(s[base + t]) : 0u;             // pad key 0: below all
    int i1 = t + 1024;
    u32 sk1 = (i1 < n_per) ? ford(s[base + i1]) : 0u;
    e0 = ((u64)sk0 << 32) | (u32)(0xFFFFFFFFu - (u32)t);        // tie -> lower idx first
    e1 = ((u64)sk1 << 32) | (u32)(0xFFFFFFFFu - (u32)i1);
  }

  for (int kk = 2; kk <= 2048; kk <<= 1) {
    int j = kk >> 1;
    if (j == 1024) {                     // partner of element t is element t+1024: local
      u64 mx = e0 > e1 ? e0 : e1;
      u64 mn = e0 > e1 ? e1 : e0;
      e0 = mx; e1 = mn;
      j >>= 1;
    }
    for (; j >= 64; j >>= 1) {           // cross-wave: LDS exchange
      __syncthreads();                   // prior pass's reads complete before overwrite
      kv[t] = e0; kv[t + 1024] = e1;
      __syncthreads();
      u64 p0 = kv[t ^ j], p1 = kv[(t + 1024) ^ j];
      int i1 = t + 1024;
      bool km0 = (((t  & kk) == 0) == ((t  & j) == 0));
      bool km1 = (((i1 & kk) == 0) == ((i1 & j) == 0));
      e0 = km0 ? (e0 > p0 ? e0 : p0) : (e0 < p0 ? e0 : p0);
      e1 = km1 ? (e1 > p1 ? e1 : p1) : (e1 < p1 ? e1 : p1);
    }
    for (; j >= 1; j >>= 1) {            // intra-wave: shuffle exchange, no barriers
      u64 p0 = shfl_xor_u64(e0, j);
      u64 p1 = shfl_xor_u64(e1, j);
      int i1 = t + 1024;
      bool km0 = (((t  & kk) == 0) == ((t  & j) == 0));
      bool km1 = (((i1 & kk) == 0) == ((i1 & j) == 0));
      e0 = km0 ? (e0 > p0 ? e0 : p0) : (e0 < p0 ? e0 : p0);
      e1 = km1 ? (e1 > p1 ? e1 : p1) : (e1 < p1 ? e1 : p1);
    }
  }

  // element i holds rank i (descending): e0 = rank t, e1 = rank t+1024
  if (t < k) {
    int old0 = (int)(0xFFFFFFFFu - (u32)(e0 & 0xFFFFFFFFu));
    perm[b * k + t] = base + old0;
    new_id[base + old0] = b * k + t;
  }
  int r1 = t + 1024;
  if (r1 < k) {
    int old1 = (int)(0xFFFFFFFFu - (u32)(e1 & 0xFFFFFFFFu));
    perm[b * k + r1] = base + old1;
    new_id[base + old1] = b * k + r1;
  }
}

// fused post-pool: WIDE gather+readout AND edge remap in ONE launch (measured good in
// R11's non-GAT portion ~320us; R10 narrow fusion and R12 spin fusion both regressed).
// grid: dim3(32, gather_rows [+ REMAP_Y when do_remap]).
__global__ void k_post(const float* __restrict__ hin, const float* __restrict__ s,
                       const int* __restrict__ perm, float* __restrict__ hout,
                       int k, int gather_rows,
                       float* __restrict__ rsum, u32* __restrict__ rmaxI,
                       int* __restrict__ src, int* __restrict__ dst, int* __restrict__ em,
                       const int* __restrict__ new_id, int* __restrict__ cnt,
                       int* __restrict__ csr, int do_remap) {
  __shared__ float ps[256], pm[256];
  int b = blockIdx.x, yy = blockIdx.y, t = threadIdx.x;
  if (yy < gather_rows) {
    int i = yy * 4 + (t >> 6);            // local kept-node index
    int c = t & 63;
    bool valid = i < k;
    float v = 0.f;
    if (valid) {
      int g = perm[b * k + i];
      v = hin[(size_t)g * 64 + c] * s[g];
      hout[((size_t)b * k + i) * 64 + c] = v;
    }
    ps[t] = valid ? v : 0.f;
    pm[t] = valid ? v : -INFINITY;
    __syncthreads();
    if (t < 64) {
      float s4 = ps[t] + ps[t + 64] + ps[t + 128] + ps[t + 192];
      float m4 = fmaxf(fmaxf(pm[t], pm[t + 64]), fmaxf(pm[t + 128], pm[t + 192]));
      atomicAdd(&rsum[b * 64 + t], s4);
      atomicMax(&rmaxI[b * 64 + t], ford(m4));
    }
  } else if (do_remap) {
    int e = ((yy - gather_rows) * 32 + b) * 256 + t;
    if (e < E_TOT) {
      int ns = new_id[src[e]], nd = new_id[dst[e]];
      int mm = em[e] && ns >= 0 && nd >= 0;
      src[e] = mm ? ns : 0;
      dst[e] = mm ? nd : 0;
      em[e] = mm;
      if (mm) {
        int pos = atomicAdd(&cnt[nd], 1);
        if (pos < MAXDEG) csr[nd * MAXDEG + pos] = e;
      }
    }
  }
}

// MLP with readout finalization folded in: reads [rsum|rmaxI] x 3 layers directly
__global__ void k_mlp(const char* __restrict__ rblk,
                      const float* __restrict__ W1, const float* __restrict__ b1,
                      const float* __restrict__ W2, const float* __restrict__ b2,
                      const float* __restrict__ W3, const float* __restrict__ b3,
                      float* __restrict__ out) {
  __shared__ float v0[128], v1[64], v2[64], lgts[16];
  int b = blockIdx.x, t = threadIdx.x;   // 64 threads
  const float* rs0 = (const float*)rblk;
  const u32*   rm0 = (const u32*)(rblk + 32 * 64 * 4);
  const float* rs1 = (const float*)(rblk + 32 * 128 * 4);
  const u32*   rm1 = (const u32*)(rblk + 32 * 128 * 4 + 32 * 64 * 4);
  const float* rs2 = (const float*)(rblk + 2 * 32 * 128 * 4);
  const u32*   rm2 = (const u32*)(rblk + 2 * 32 * 128 * 4 + 32 * 64 * 4);
  v0[t] = rs0[b * 64 + t] / 1268.f + rs1[b * 64 + t] / 1015.f + rs2[b * 64 + t] / 812.f;
  v0[64 + t] = ford_inv(rm0[b * 64 + t]) + ford_inv(rm1[b * 64 + t]) + ford_inv(rm2[b * 64 + t]);
  __syncthreads();
  float a = b1[t];
  for (int i = 0; i < 128; ++i) a += v0[i] * W1[i * 64 + t];
  v1[t] = fmaxf(a, 0.f);
  __syncthreads();
  a = b2[t];
  for (int i = 0; i < 64; ++i) a += v1[i] * W2[i * 64 + t];
  v2[t] = fmaxf(a, 0.f);
  __syncthreads();
  if (t < 16) {
    a = b3[t];
    for (int i = 0; i < 64; ++i) a += v2[i] * W3[i * 16 + t];
    lgts[t] = a;
  }
  __syncthreads();
  if (t == 0) {
    float m = lgts[0];
    for (int j = 1; j < 16; ++j) m = fmaxf(m, lgts[j]);
    float ex[16], sum = 0.f;
    for (int j = 0; j < 16; ++j) { ex[j] = expf(lgts[j] - m); sum += ex[j]; }
    for (int j = 0; j < 16; ++j) out[b * 16 + j] = ex[j] / sum;
  }
}

extern "C" void kernel_launch(void* const* d_in, const int* in_sizes, int n_in,
                              void* d_out, int out_size, void* d_ws, size_t ws_size,
                              hipStream_t stream) {
  (void)in_sizes; (void)n_in; (void)out_size; (void)ws_size;
  const float* x  = (const float*)d_in[0];      // [NMAX, 32] f32
  const float* ea = (const float*)d_in[1];      // [E, 8]     f32
  const int*   ei = (const int*)d_in[2];        // [2, E]

  const float *gWl[3], *gbl[3], *gWr[3], *gbr[3], *gWe[3], *gatt[3], *gb[3], *pw[3];
  for (int l = 0; l < 3; ++l) {
    int p0 = 4 + 7 * l;
    gWl[l]  = (const float*)d_in[p0 + 0];
    gbl[l]  = (const float*)d_in[p0 + 1];
    gWr[l]  = (const float*)d_in[p0 + 2];
    gbr[l]  = (const float*)d_in[p0 + 3];
    gWe[l]  = (const float*)d_in[p0 + 4];
    gatt[l] = (const float*)d_in[p0 + 5];
    gb[l]   = (const float*)d_in[p0 + 6];
    pw[l]   = (const float*)d_in[25 + l];
  }
  const float* fc1W = (const float*)d_in[28];
  const float* fc1b = (const float*)d_in[29];
  const float* fc2W = (const float*)d_in[30];
  const float* fc2b = (const float*)d_in[31];
  const float* fc3W = (const float*)d_in[32];
  const float* fc3b = (const float*)d_in[33];

  // ---- workspace carve. cnt|rblk|csr CONTIGUOUS (all sizes %256==0): ONE memset ----
  char* w = (char*)d_ws;
  size_t off = 0;
  auto alloc = [&](size_t bytes) -> void* {
    void* p = w + off;
    off += (bytes + 255) & ~(size_t)255;
    return p;
  };
  float* hbuf = (float*)alloc((size_t)B_ * 1268 * 64 * 4); // pooled features (max K1)
  float* xl   = (float*)alloc((size_t)NMAX * 256 * 4);     // source transform [N,256]
  float* xr   = (float*)alloc((size_t)NMAX * 256 * 4);     // target transform [N,256]
  float* nacc = (float*)alloc((size_t)NMAX * 64 * 4);      // fused GAT output (pre-pool)
  int*   cnt  = (int*)alloc((size_t)NMAX * 4);             // CSR degree counters
  char*  rblk = (char*)alloc(3 * 32 * 128 * 4);            // per-layer [rsum][rmaxI] x3
  int*   csr  = (int*)alloc((size_t)NMAX * MAXDEG * 4);
  float* sbuf = (float*)alloc((size_t)NMAX * 4);
  int* src    = (int*)alloc((size_t)E_TOT * 4);
  int* dst    = (int*)alloc((size_t)E_TOT * 4);
  int* em     = (int*)alloc((size_t)E_TOT * 4);
  int* new_id = (int*)alloc((size_t)NMAX * 4);
  int* perm   = (int*)alloc((size_t)32 * 1268 * 4);

  // one-time zero of cnt + rblk + csr (csr zero => every slot is an in-bounds edge id
  // forever, enabling k_gat_fused's unconditional csr/srcv prefetch)
  size_t zbytes = (size_t)NMAX * 4 + 3 * 32 * 128 * 4 + (size_t)NMAX * MAXDEG * 4;
  hipMemsetAsync(cnt, 0, zbytes, stream);
  k_edge_init_csr<<<CDIV(E_TOT, 256), 256, 0, stream>>>(ei, src, dst, em, cnt, csr);

  const int Ns[3]    = {50688, 40576, 32480};   // B*N0, B*K1, B*K2 (all %16==0)
  const int npers[3] = {1584, 1268, 1015};
  const int ks[3]    = {1268, 1015, 812};
  const int GAT_BLOCKS = 2048;                  // 8 XCD x 4 graphs x 64 blocks

  for (int l = 0; l < 3; ++l) {
    int N = Ns[l];
    const float* hin = (l == 0) ? x : hbuf;
    float* rsum = (float*)(rblk + l * 32 * 128 * 4);
    u32* rmaxI  = (u32*)(rblk + l * 32 * 128 * 4 + 32 * 64 * 4);
    if (l == 0)
      k_transform_t<32><<<N / 16, 256, 0, stream>>>(hin, gWl[l], gbl[l], gWr[l], gbr[l], xl, xr);
    else
      k_transform_t<64><<<N / 16, 256, 0, stream>>>(hin, gWl[l], gbl[l], gWr[l], gbr[l], xl, xr);
    k_gat_fused<<<GAT_BLOCKS, 256, 0, stream>>>(src, cnt, csr, ea, gWe[l], gatt[l],
                                                xl, xr, gb[l], pw[l], nacc, sbuf, npers[l]);
    k_topk<<<32, 1024, 0, stream>>>(sbuf, npers[l], ks[l], perm, new_id, cnt);
    int grows = CDIV(ks[l], 4);
    dim3 pgrid(32, grows + (l < 2 ? REMAP_Y : 0));
    k_post<<<pgrid, 256, 0, stream>>>(nacc, sbuf, perm, hbuf, ks[l], grows, rsum, rmaxI,
                                      src, dst, em, new_id, cnt, csr, (l < 2) ? 1 : 0);
  }
  k_mlp<<<32, 64, 0, stream>>>(rblk, fc1W, fc1b, fc2W, fc2b, fc3W, fc3b, (float*)d_out);
}

// Round 15
// 470.893 us; speedup vs baseline: 1.7083x; 1.0147x over previous
//
#include <hip/hip_runtime.h>

typedef unsigned short u16;
typedef unsigned int u32;
typedef unsigned long long u64;

#define E_TOT 202752   // B*N0*DEG = 32*1584*4
#define NMAX  50688    // B*N0
#define HEADS 4
#define B_    32
#define MAXDEG 32      // Poisson(4) in-degree: P(>=32) ~ 1e-18/node — safe bucket
#define REMAP_Y 25     // CDIV(E_TOT, 32*256)
#define TRE_TBLK 3168  // transform blocks for L0 = NMAX/16
#define TRE_EBLK 792   // edge-init blocks = CDIV(E_TOT,256)

#define CDIV(a,b) (((a)+(b)-1)/(b))

// order-preserving float->uint map (monotonic); code 0 is below any real float's code
__device__ __forceinline__ u32 ford(float f) {
  u32 u = __float_as_uint(f);
  return (u & 0x80000000u) ? ~u : (u | 0x80000000u);
}
__device__ __forceinline__ float ford_inv(u32 u) {
  u32 b = (u & 0x80000000u) ? (u ^ 0x80000000u) : ~u;
  return __uint_as_float(b);
}

// DPP row-rotate (16-lane row) move; CTRL = 0x120 | n for row_ror:n
template <int CTRL>
__device__ __forceinline__ float dpp_mov(float x) {
  return __int_as_float(__builtin_amdgcn_mov_dpp(__float_as_int(x), CTRL, 0xF, 0xF, false));
}
// sum over each 16-lane row via VALU-pipe rotations (no DS pipe on the hot path)
__device__ __forceinline__ float row16_sum(float v) {
  v += dpp_mov<0x121>(v);   // row_ror:1
  v += dpp_mov<0x122>(v);   // row_ror:2
  v += dpp_mov<0x124>(v);   // row_ror:4
  v += dpp_mov<0x128>(v);   // row_ror:8
  return v;
}

__device__ __forceinline__ u64 shfl_xor_u64(u64 v, int mask) {
  int lo = __shfl_xor((int)(u32)(v & 0xFFFFFFFFu), mask, 64);
  int hi = __shfl_xor((int)(u32)(v >> 32), mask, 64);
  return ((u64)(u32)hi << 32) | (u32)lo;
}

// ---------- FUSED: node transform L0 (FIN=32) + edge-array/CSR init in ONE launch.
// The two are fully independent (the only such pair in the dependency graph), so
// fusing by block-range costs nothing and saves one dispatch boundary.
// blocks [0,TRE_TBLK): transform 16 nodes each; blocks [TRE_TBLK,+TRE_EBLK): edges.
__global__ void k_tre(const float* __restrict__ hin,
                      const float* __restrict__ Wl, const float* __restrict__ bl,
                      const float* __restrict__ Wr, const float* __restrict__ br,
                      float* __restrict__ xl, float* __restrict__ xr,
                      const int* __restrict__ ei, int* __restrict__ src,
                      int* __restrict__ dst, int* __restrict__ em,
                      int* __restrict__ cnt, int* __restrict__ csr) {
  __shared__ float xs[32][20];
  int j = threadIdx.x;
  if (blockIdx.x >= TRE_TBLK) {          // ---- edge-init role ----
    int e = (blockIdx.x - TRE_TBLK) * 256 + j;
    if (e >= E_TOT) return;
    int s = ei[e], d = ei[E_TOT + e];
    src[e] = s;
    dst[e] = d;
    em[e] = 1;
    int pos = atomicAdd(&cnt[d], 1);
    if (pos < MAXDEG) csr[d * MAXDEG + pos] = e;
    return;
  }
  // ---- transform role (verified k_transform_t<32> body) ----
  int n0 = blockIdx.x * 16;
  for (int t = j; t < 16 * 32; t += 256) {
    int nd = t >> 5, f = t & 31;
    xs[f][nd] = hin[(size_t)(n0 + nd) * 32 + f];
  }
  __syncthreads();
  float al[16], ar[16];
  float blv = bl[j], brv = br[j];
#pragma unroll
  for (int t = 0; t < 16; ++t) { al[t] = blv; ar[t] = brv; }
  for (int i = 0; i < 32; ++i) {
    float wl = Wl[i * 256 + j], wr = Wr[i * 256 + j];
    float4 x0 = *(const float4*)&xs[i][0];
    float4 x1 = *(const float4*)&xs[i][4];
    float4 x2 = *(const float4*)&xs[i][8];
    float4 x3 = *(const float4*)&xs[i][12];
    al[0]  += x0.x * wl; ar[0]  += x0.x * wr;
    al[1]  += x0.y * wl; ar[1]  += x0.y * wr;
    al[2]  += x0.z * wl; ar[2]  += x0.z * wr;
    al[3]  += x0.w * wl; ar[3]  += x0.w * wr;
    al[4]  += x1.x * wl; ar[4]  += x1.x * wr;
    al[5]  += x1.y * wl; ar[5]  += x1.y * wr;
    al[6]  += x1.z * wl; ar[6]  += x1.z * wr;
    al[7]  += x1.w * wl; ar[7]  += x1.w * wr;
    al[8]  += x2.x * wl; ar[8]  += x2.x * wr;
    al[9]  += x2.y * wl; ar[9]  += x2.y * wr;
    al[10] += x2.z * wl; ar[10] += x2.z * wr;
    al[11] += x2.w * wl; ar[11] += x2.w * wr;
    al[12] += x3.x * wl; ar[12] += x3.x * wr;
    al[13] += x3.y * wl; ar[13] += x3.y * wr;
    al[14] += x3.z * wl; ar[14] += x3.z * wr;
    al[15] += x3.w * wl; ar[15] += x3.w * wr;
  }
#pragma unroll
  for (int t = 0; t < 16; ++t) {
    xl[(size_t)(n0 + t) * 256 + j] = al[t];
    xr[(size_t)(n0 + t) * 256 + j] = ar[t];
  }
}

// ---------- node transform for layers 1,2 (FIN=64) — unchanged verified version ----
template <int FIN>
__global__ void k_transform_t(const float* __restrict__ hin,
                              const float* __restrict__ Wl, const float* __restrict__ bl,
                              const float* __restrict__ Wr, const float* __restrict__ br,
                              float* __restrict__ xl, float* __restrict__ xr) {
  __shared__ float xs[FIN][20];
  int n0 = blockIdx.x * 16, j = threadIdx.x;   // 256 threads
  for (int t = j; t < 16 * FIN; t += 256) {
    int nd = t >> (FIN == 32 ? 5 : 6), f = t & (FIN - 1);
    xs[f][nd] = hin[(size_t)(n0 + nd) * FIN + f];
  }
  __syncthreads();
  float al[16], ar[16];
  float blv = bl[j], brv = br[j];
#pragma unroll
  for (int t = 0; t < 16; ++t) { al[t] = blv; ar[t] = brv; }
  for (int i = 0; i < FIN; ++i) {
    float wl = Wl[i * 256 + j], wr = Wr[i * 256 + j];
    float4 x0 = *(const float4*)&xs[i][0];     // broadcast b128 reads
    float4 x1 = *(const float4*)&xs[i][4];
    float4 x2 = *(const float4*)&xs[i][8];
    float4 x3 = *(const float4*)&xs[i][12];
    al[0]  += x0.x * wl; ar[0]  += x0.x * wr;
    al[1]  += x0.y * wl; ar[1]  += x0.y * wr;
    al[2]  += x0.z * wl; ar[2]  += x0.z * wr;
    al[3]  += x0.w * wl; ar[3]  += x0.w * wr;
    al[4]  += x1.x * wl; ar[4]  += x1.x * wr;
    al[5]  += x1.y * wl; ar[5]  += x1.y * wr;
    al[6]  += x1.z * wl; ar[6]  += x1.z * wr;
    al[7]  += x1.w * wl; ar[7]  += x1.w * wr;
    al[8]  += x2.x * wl; ar[8]  += x2.x * wr;
    al[9]  += x2.y * wl; ar[9]  += x2.y * wr;
    al[10] += x2.z * wl; ar[10] += x2.z * wr;
    al[11] += x2.w * wl; ar[11] += x2.w * wr;
    al[12] += x3.x * wl; ar[12] += x3.x * wr;
    al[13] += x3.y * wl; ar[13] += x3.y * wr;
    al[14] += x3.z * wl; ar[14] += x3.z * wr;
    al[15] += x3.w * wl; ar[15] += x3.w * wr;
  }
#pragma unroll
  for (int t = 0; t < 16; ++t) {
    xl[(size_t)(n0 + t) * 256 + j] = al[t];
    xr[(size_t)(n0 + t) * 256 + j] = ar[t];
  }
}

// ---------- fused GATv2: R6-verified math + chunk-0 prefetch (R11-verified math) ----
// R11's prefetch passed correctness but SPILLED: default codegen targets 8 waves/SIMD
// (64-VGPR cap) and R6 already uses 56. __launch_bounds__(256,4) raises the cap to
// 128 VGPR (est. use ~100) so the 48-VGPR prefetch buffers live in registers.
// VALUBusy=48% at full residency says TLP can't hide the gather latency; trading the
// occupancy CAP (not achieved occupancy) for per-wave MLP is the experiment.
// Spill canary: WRITE_SIZE must stay ~13 MB (R11's spill showed as 37 MB).
__global__ __launch_bounds__(256, 4) void k_gat_fused(
                            const int* __restrict__ srcv, const int* __restrict__ cnt,
                            const int* __restrict__ csr, const float* __restrict__ ea,
                            const float* __restrict__ We, const float* __restrict__ att,
                            const float* __restrict__ xl, const float* __restrict__ xr,
                            const float* __restrict__ bias, const float* __restrict__ pwv,
                            float* __restrict__ out, float* __restrict__ sc,
                            int n_per) {
  int b = blockIdx.x;
  int xcd = b & 7;
  int jj = b >> 3;                                 // 0..255 within XCD
  int g = xcd + 8 * (jj >> 6);                     // graph 0..31, g%8 == xcd
  int wv = ((jj & 63) << 2) + (threadIdx.x >> 6);  // wave-in-graph 0..255
  int lane = threadIdx.x & 63;
  int cg = lane & 15;
  int cb = (lane >> 4) * 64 + cg * 4;              // this lane's 4 channels
  int npw = CDIV(n_per, 256);
  int l0 = wv * npw, l1 = min(n_per, l0 + npw);
  if (l0 >= n_per) return;
  int n0 = g * n_per + l0, n1 = g * n_per + l1;
  // per-layer constants, hoisted once per wave
  float4 at4 = *(const float4*)(att + cb);
  float4 w0 = *(const float4*)(We + 0 * 256 + cb);
  float4 w1 = *(const float4*)(We + 1 * 256 + cb);
  float4 w2 = *(const float4*)(We + 2 * 256 + cb);
  float4 w3 = *(const float4*)(We + 3 * 256 + cb);
  float4 w4_ = *(const float4*)(We + 4 * 256 + cb);
  float4 w5 = *(const float4*)(We + 5 * 256 + cb);
  float4 w6 = *(const float4*)(We + 6 * 256 + cb);
  float4 w7 = *(const float4*)(We + 7 * 256 + cb);
  float4 bi4 = *(const float4*)(bias + cg * 4);
  float4 pw4 = *(const float4*)(pwv + cg * 4);
  float wn = pw4.x * pw4.x + pw4.y * pw4.y + pw4.z * pw4.z + pw4.w * pw4.w;
  wn += __shfl_xor(wn, 1, 64); wn += __shfl_xor(wn, 2, 64);
  wn += __shfl_xor(wn, 4, 64); wn += __shfl_xor(wn, 8, 64);
  float isq = 1.f / sqrtf(wn);

  // prologue: node n0's metadata + xr row + chunk-0 gather in flight
  int degc = cnt[n0];
  int e_c = (lane < MAXDEG) ? csr[n0 * MAXDEG + lane] : 0;
  int s_c = srcv[e_c];                            // garbage beyond deg: masked later
  float4 xdc = *(const float4*)(xr + (size_t)n0 * 256 + cb);
  float4 pxs[4], pa0[4], pa1[4];                  // chunk-0 prefetch buffers (48 VGPR)
#pragma unroll
  for (int j = 0; j < 4; ++j) {
    int ee = __builtin_amdgcn_readlane(e_c, j);   // csr zero-init: always in-bounds
    int ss = __builtin_amdgcn_readlane(s_c, j);
    pxs[j] = *(const float4*)(xl + (size_t)ss * 256 + cb);
    pa0[j] = *(const float4*)(ea + (size_t)ee * 8);
    pa1[j] = *(const float4*)(ea + (size_t)ee * 8 + 4);
  }

  for (int n = n0; n < n1; ++n) {
    // meta for node n+1 (drains while we compute node n)
    int degn = 0, e_n = 0, s_n = 0;
    float4 xdn = xdc;
    if (n + 1 < n1) {
      degn = cnt[n + 1];
      e_n = (lane < MAXDEG) ? csr[(n + 1) * MAXDEG + lane] : 0;
      s_n = srcv[e_n];
      xdn = *(const float4*)(xr + (size_t)(n + 1) * 256 + cb);
    }
    int deg = min(degc, MAXDEG);
    float4 xd4 = xdc;
    float m = -INFINITY, l = 0.f;
    float ox = 0.f, oy = 0.f, oz = 0.f, ow = 0.f;

    if (deg > 0) {
      // ---- chunk 0 from the prefetch buffers (loaded last iteration) ----
      int c0 = deg < 4 ? deg : 4;
      float v[4];
#pragma unroll
      for (int j = 0; j < 4; ++j) {
        if (j < c0) {
          float e0 = pa0[j].x * w0.x + pa0[j].y * w1.x + pa0[j].z * w2.x + pa0[j].w * w3.x
                   + pa1[j].x * w4_.x + pa1[j].y * w5.x + pa1[j].z * w6.x + pa1[j].w * w7.x;
          float e1 = pa0[j].x * w0.y + pa0[j].y * w1.y + pa0[j].z * w2.y + pa0[j].w * w3.y
                   + pa1[j].x * w4_.y + pa1[j].y * w5.y + pa1[j].z * w6.y + pa1[j].w * w7.y;
          float e2 = pa0[j].x * w0.z + pa0[j].y * w1.z + pa0[j].z * w2.z + pa0[j].w * w3.z
                   + pa1[j].x * w4_.z + pa1[j].y * w5.z + pa1[j].z * w6.z + pa1[j].w * w7.z;
          float e3 = pa0[j].x * w0.w + pa0[j].y * w1.w + pa0[j].z * w2.w + pa0[j].w * w3.w
                   + pa1[j].x * w4_.w + pa1[j].y * w5.w + pa1[j].z * w6.w + pa1[j].w * w7.w;
          float m0 = pxs[j].x + xd4.x + e0; m0 = (m0 >= 0.f) ? m0 : 0.2f * m0;  // leaky
          float m1 = pxs[j].y + xd4.y + e1; m1 = (m1 >= 0.f) ? m1 : 0.2f * m1;
          float m2 = pxs[j].z + xd4.z + e2; m2 = (m2 >= 0.f) ? m2 : 0.2f * m2;
          float m3 = pxs[j].w + xd4.w + e3; m3 = (m3 >= 0.f) ? m3 : 0.2f * m3;
          float d = at4.x * m0 + at4.y * m1 + at4.z * m2 + at4.w * m3;
          v[j] = row16_sum(d);
        } else {
          v[j] = -INFINITY;              // pad: p=exp(-inf-nm)=0, no contribution
        }
      }
      float vm = fmaxf(fmaxf(v[0], v[1]), fmaxf(v[2], v[3]));
      float nm = vm;                     // m was -inf: no rescale term needed
      float p0 = __expf(v[0] - nm), p1 = __expf(v[1] - nm);
      float p2 = __expf(v[2] - nm), p3 = __expf(v[3] - nm);
      ox = (p0 * pxs[0].x + p1 * pxs[1].x) + (p2 * pxs[2].x + p3 * pxs[3].x);
      oy = (p0 * pxs[0].y + p1 * pxs[1].y) + (p2 * pxs[2].y + p3 * pxs[3].y);
      oz = (p0 * pxs[0].z + p1 * pxs[1].z) + (p2 * pxs[2].z + p3 * pxs[3].z);
      ow = (p0 * pxs[0].w + p1 * pxs[1].w) + (p2 * pxs[2].w + p3 * pxs[3].w);
      l = (p0 + p1) + (p2 + p3);
      m = nm;
      // ---- inline chunks for deg > 4 (R6-verified path, reads e_c/s_c) ----
      for (int i0 = 4; i0 < deg; i0 += 4) {
        int c0i = deg - i0; if (c0i > 4) c0i = 4;
        float4 ixs[4], ia0[4], ia1[4];
#pragma unroll
        for (int j = 0; j < 4; ++j) {
          int idx = (j < c0i) ? (i0 + j) : i0;
          int e = __builtin_amdgcn_readlane(e_c, idx);
          int s = __builtin_amdgcn_readlane(s_c, idx);
          ixs[j] = *(const float4*)(xl + (size_t)s * 256 + cb);
          ia0[j] = *(const float4*)(ea + (size_t)e * 8);
          ia1[j] = *(const float4*)(ea + (size_t)e * 8 + 4);
        }
        float vv[4];
#pragma unroll
        for (int j = 0; j < 4; ++j) {
          if (j < c0i) {
            float e0 = ia0[j].x * w0.x + ia0[j].y * w1.x + ia0[j].z * w2.x + ia0[j].w * w3.x
                     + ia1[j].x * w4_.x + ia1[j].y * w5.x + ia1[j].z * w6.x + ia1[j].w * w7.x;
            float e1 = ia0[j].x * w0.y + ia0[j].y * w1.y + ia0[j].z * w2.y + ia0[j].w * w3.y
                     + ia1[j].x * w4_.y + ia1[j].y * w5.y + ia1[j].z * w6.y + ia1[j].w * w7.y;
            float e2 = ia0[j].x * w0.z + ia0[j].y * w1.z + ia0[j].z * w2.z + ia0[j].w * w3.z
                     + ia1[j].x * w4_.z + ia1[j].y * w5.z + ia1[j].z * w6.z + ia1[j].w * w7.z;
            float e3 = ia0[j].x * w0.w + ia0[j].y * w1.w + ia0[j].z * w2.w + ia0[j].w * w3.w
                     + ia1[j].x * w4_.w + ia1[j].y * w5.w + ia1[j].z * w6.w + ia1[j].w * w7.w;
            float m0 = ixs[j].x + xd4.x + e0; m0 = (m0 >= 0.f) ? m0 : 0.2f * m0;
            float m1 = ixs[j].y + xd4.y + e1; m1 = (m1 >= 0.f) ? m1 : 0.2f * m1;
            float m2 = ixs[j].z + xd4.z + e2; m2 = (m2 >= 0.f) ? m2 : 0.2f * m2;
            float m3 = ixs[j].w + xd4.w + e3; m3 = (m3 >= 0.f) ? m3 : 0.2f * m3;
            float d = at4.x * m0 + at4.y * m1 + at4.z * m2 + at4.w * m3;
            vv[j] = row16_sum(d);
          } else {
            vv[j] = -INFINITY;
          }
        }
        float vmi = fmaxf(fmaxf(vv[0], vv[1]), fmaxf(vv[2], vv[3]));
        float nmi = fmaxf(m, vmi);
        float scale = __expf(m - nmi);
        float q0 = __expf(vv[0] - nmi), q1 = __expf(vv[1] - nmi);
        float q2 = __expf(vv[2] - nmi), q3 = __expf(vv[3] - nmi);
        ox = ox * scale + ((q0 * ixs[0].x + q1 * ixs[1].x) + (q2 * ixs[2].x + q3 * ixs[3].x));
        oy = oy * scale + ((q0 * ixs[0].y + q1 * ixs[1].y) + (q2 * ixs[2].y + q3 * ixs[3].y));
        oz = oz * scale + ((q0 * ixs[0].z + q1 * ixs[1].z) + (q2 * ixs[2].z + q3 * ixs[3].z));
        ow = ow * scale + ((q0 * ixs[0].w + q1 * ixs[1].w) + (q2 * ixs[2].w + q3 * ixs[3].w));
        l = l * scale + ((q0 + q1) + (q2 + q3));
        m = nmi;
      }
    }

    // refill prefetch buffers for node n+1 (e_n/s_n issued at loop top — arrived or
    // nearly so). Loads drain under the epilogue below. Last iter: e_n=0 -> in-bounds
    // dummy loads, values unused.
#pragma unroll
    for (int j = 0; j < 4; ++j) {
      int ee = __builtin_amdgcn_readlane(e_n, j);
      int ss = __builtin_amdgcn_readlane(s_n, j);
      pxs[j] = *(const float4*)(xl + (size_t)ss * 256 + cb);
      pa0[j] = *(const float4*)(ea + (size_t)ee * 8);
      pa1[j] = *(const float4*)(ea + (size_t)ee * 8 + 4);
    }

    // epilogue: per-head y = O/den, then 0.25 * head-sum  (deg==0 -> l=0 -> y=0)
    float inv = 0.25f / fmaxf(l, 1e-16f);
    float r0 = ox * inv, r1 = oy * inv, r2 = oz * inv, r3 = ow * inv;
    r0 += __shfl_xor(r0, 16, 64); r0 += __shfl_xor(r0, 32, 64);
    r1 += __shfl_xor(r1, 16, 64); r1 += __shfl_xor(r1, 32, 64);
    r2 += __shfl_xor(r2, 16, 64); r2 += __shfl_xor(r2, 32, 64);
    r3 += __shfl_xor(r3, 16, 64); r3 += __shfl_xor(r3, 32, 64);
    float rr0 = fmaxf(r0 + bi4.x, 0.f), rr1 = fmaxf(r1 + bi4.y, 0.f);
    float rr2 = fmaxf(r2 + bi4.z, 0.f), rr3 = fmaxf(r3 + bi4.w, 0.f);
    if (lane < 16) *(float4*)(out + (size_t)n * 64 + cg * 4) = float4{rr0, rr1, rr2, rr3};
    // topk score: s = tanh(h.w / ||w||)
    float dot = rr0 * pw4.x + rr1 * pw4.y + rr2 * pw4.z + rr3 * pw4.w;
    dot += __shfl_xor(dot, 1, 64);
    dot += __shfl_xor(dot, 2, 64);
    dot += __shfl_xor(dot, 4, 64);
    dot += __shfl_xor(dot, 8, 64);
    if (lane == 0) sc[n] = tanhf(dot * isq);
    // rotate pipeline registers
    degc = degn; e_c = e_n; s_c = s_n; xdc = xdn;
  }
}

// stable descending top-k per graph — u64 keys (ford(score)<<32 | ~idx).
// Hybrid bitonic over 2048 elements, 2 elements/thread in registers (measured R6).
// Also zeroes cnt[0, B*k) for the next layer (replaces a hipMemsetAsync).
__global__ __launch_bounds__(1024) void k_topk(const float* __restrict__ s, int n_per,
                                               int k,
                                               int* __restrict__ perm, int* __restrict__ new_id,
                                               int* __restrict__ cnt) {
  __shared__ u64 kv[2048];
  int b = blockIdx.x, t = threadIdx.x;
  int base = b * n_per;
  for (int i = t; i < n_per; i += 1024) new_id[base + i] = -1;
  for (int i = t; i < k; i += 1024) cnt[b * k + i] = 0;   // next layer's CSR counters

  u64 e0, e1;
  {
    u32 sk0 = (t < n_per) ? ford(s[base + t]) : 0u;             // pad key 0: below all
    int i1 = t + 1024;
    u32 sk1 = (i1 < n_per) ? ford(s[base + i1]) : 0u;
    e0 = ((u64)sk0 << 32) | (u32)(0xFFFFFFFFu - (u32)t);        // tie -> lower idx first
    e1 = ((u64)sk1 << 32) | (u32)(0xFFFFFFFFu - (u32)i1);
  }

  for (int kk = 2; kk <= 2048; kk <<= 1) {
    int j = kk >> 1;
    if (j == 1024) {                     // partner of element t is element t+1024: local
      u64 mx = e0 > e1 ? e0 : e1;
      u64 mn = e0 > e1 ? e1 : e0;
      e0 = mx; e1 = mn;
      j >>= 1;
    }
    for (; j >= 64; j >>= 1) {           // cross-wave: LDS exchange
      __syncthreads();                   // prior pass's reads complete before overwrite
      kv[t] = e0; kv[t + 1024] = e1;
      __syncthreads();
      u64 p0 = kv[t ^ j], p1 = kv[(t + 1024) ^ j];
      int i1 = t + 1024;
      bool km0 = (((t  & kk) == 0) == ((t  & j) == 0));
      bool km1 = (((i1 & kk) == 0) == ((i1 & j) == 0));
      e0 = km0 ? (e0 > p0 ? e0 : p0) : (e0 < p0 ? e0 : p0);
      e1 = km1 ? (e1 > p1 ? e1 : p1) : (e1 < p1 ? e1 : p1);
    }
    for (; j >= 1; j >>= 1) {            // intra-wave: shuffle exchange, no barriers
      u64 p0 = shfl_xor_u64(e0, j);
      u64 p1 = shfl_xor_u64(e1, j);
      int i1 = t + 1024;
      bool km0 = (((t  & kk) == 0) == ((t  & j) == 0));
      bool km1 = (((i1 & kk) == 0) == ((i1 & j) == 0));
      e0 = km0 ? (e0 > p0 ? e0 : p0) : (e0 < p0 ? e0 : p0);
      e1 = km1 ? (e1 > p1 ? e1 : p1) : (e1 < p1 ? e1 : p1);
    }
  }

  // element i holds rank i (descending): e0 = rank t, e1 = rank t+1024
  if (t < k) {
    int old0 = (int)(0xFFFFFFFFu - (u32)(e0 & 0xFFFFFFFFu));
    perm[b * k + t] = base + old0;
    new_id[base + old0] = b * k + t;
  }
  int r1 = t + 1024;
  if (r1 < k) {
    int old1 = (int)(0xFFFFFFFFu - (u32)(e1 & 0xFFFFFFFFu));
    perm[b * k + r1] = base + old1;
    new_id[base + old1] = b * k + r1;
  }
}

// fused post-pool: WIDE gather+readout AND edge remap in ONE launch (measured good;
// R10 narrow fusion and R12 spin fusion both regressed — width matters).
// grid: dim3(32, gather_rows [+ REMAP_Y when do_remap]).
__global__ void k_post(const float* __restrict__ hin, const float* __restrict__ s,
                       const int* __restrict__ perm, float* __restrict__ hout,
                       int k, int gather_rows,
                       float* __restrict__ rsum, u32* __restrict__ rmaxI,
                       int* __restrict__ src, int* __restrict__ dst, int* __restrict__ em,
                       const int* __restrict__ new_id, int* __restrict__ cnt,
                       int* __restrict__ csr, int do_remap) {
  __shared__ float ps[256], pm[256];
  int b = blockIdx.x, yy = blockIdx.y, t = threadIdx.x;
  if (yy < gather_rows) {
    int i = yy * 4 + (t >> 6);            // local kept-node index
    int c = t & 63;
    bool valid = i < k;
    float v = 0.f;
    if (valid) {
      int g = perm[b * k + i];
      v = hin[(size_t)g * 64 + c] * s[g];
      hout[((size_t)b * k + i) * 64 + c] = v;
    }
    ps[t] = valid ? v : 0.f;
    pm[t] = valid ? v : -INFINITY;
    __syncthreads();
    if (t < 64) {
      float s4 = ps[t] + ps[t + 64] + ps[t + 128] + ps[t + 192];
      float m4 = fmaxf(fmaxf(pm[t], pm[t + 64]), fmaxf(pm[t + 128], pm[t + 192]));
      atomicAdd(&rsum[b * 64 + t], s4);
      atomicMax(&rmaxI[b * 64 + t], ford(m4));
    }
  } else if (do_remap) {
    int e = ((yy - gather_rows) * 32 + b) * 256 + t;
    if (e < E_TOT) {
      int ns = new_id[src[e]], nd = new_id[dst[e]];
      int mm = em[e] && ns >= 0 && nd >= 0;
      src[e] = mm ? ns : 0;
      dst[e] = mm ? nd : 0;
      em[e] = mm;
      if (mm) {
        int pos = atomicAdd(&cnt[nd], 1);
        if (pos < MAXDEG) csr[nd * MAXDEG + pos] = e;
      }
    }
  }
}

// MLP with readout finalization folded in: reads [rsum|rmaxI] x 3 layers directly
__global__ void k_mlp(const char* __restrict__ rblk,
                      const float* __restrict__ W1, const float* __restrict__ b1,
                      const float* __restrict__ W2, const float* __restrict__ b2,
                      const float* __restrict__ W3, const float* __restrict__ b3,
                      float* __restrict__ out) {
  __shared__ float v0[128], v1[64], v2[64], lgts[16];
  int b = blockIdx.x, t = threadIdx.x;   // 64 threads
  const float* rs0 = (const float*)rblk;
  const u32*   rm0 = (const u32*)(rblk + 32 * 64 * 4);
  const float* rs1 = (const float*)(rblk + 32 * 128 * 4);
  const u32*   rm1 = (const u32*)(rblk + 32 * 128 * 4 + 32 * 64 * 4);
  const float* rs2 = (const float*)(rblk + 2 * 32 * 128 * 4);
  const u32*   rm2 = (const u32*)(rblk + 2 * 32 * 128 * 4 + 32 * 64 * 4);
  v0[t] = rs0[b * 64 + t] / 1268.f + rs1[b * 64 + t] / 1015.f + rs2[b * 64 + t] / 812.f;
  v0[64 + t] = ford_inv(rm0[b * 64 + t]) + ford_inv(rm1[b * 64 + t]) + ford_inv(rm2[b * 64 + t]);
  __syncthreads();
  float a = b1[t];
  for (int i = 0; i < 128; ++i) a += v0[i] * W1[i * 64 + t];
  v1[t] = fmaxf(a, 0.f);
  __syncthreads();
  a = b2[t];
  for (int i = 0; i < 64; ++i) a += v1[i] * W2[i * 64 + t];
  v2[t] = fmaxf(a, 0.f);
  __syncthreads();
  if (t < 16) {
    a = b3[t];
    for (int i = 0; i < 64; ++i) a += v2[i] * W3[i * 16 + t];
    lgts[t] = a;
  }
  __syncthreads();
  if (t == 0) {
    float m = lgts[0];
    for (int j = 1; j < 16; ++j) m = fmaxf(m, lgts[j]);
    float ex[16], sum = 0.f;
    for (int j = 0; j < 16; ++j) { ex[j] = expf(lgts[j] - m); sum += ex[j]; }
    for (int j = 0; j < 16; ++j) out[b * 16 + j] = ex[j] / sum;
  }
}

extern "C" void kernel_launch(void* const* d_in, const int* in_sizes, int n_in,
                              void* d_out, int out_size, void* d_ws, size_t ws_size,
                              hipStream_t stream) {
  (void)in_sizes; (void)n_in; (void)out_size; (void)ws_size;
  const float* x  = (const float*)d_in[0];      // [NMAX, 32] f32
  const float* ea = (const float*)d_in[1];      // [E, 8]     f32
  const int*   ei = (const int*)d_in[2];        // [2, E]

  const float *gWl[3], *gbl[3], *gWr[3], *gbr[3], *gWe[3], *gatt[3], *gb[3], *pw[3];
  for (int l = 0; l < 3; ++l) {
    int p0 = 4 + 7 * l;
    gWl[l]  = (const float*)d_in[p0 + 0];
    gbl[l]  = (const float*)d_in[p0 + 1];
    gWr[l]  = (const float*)d_in[p0 + 2];
    gbr[l]  = (const float*)d_in[p0 + 3];
    gWe[l]  = (const float*)d_in[p0 + 4];
    gatt[l] = (const float*)d_in[p0 + 5];
    gb[l]   = (const float*)d_in[p0 + 6];
    pw[l]   = (const float*)d_in[25 + l];
  }
  const float* fc1W = (const float*)d_in[28];
  const float* fc1b = (const float*)d_in[29];
  const float* fc2W = (const float*)d_in[30];
  const float* fc2b = (const float*)d_in[31];
  const float* fc3W = (const float*)d_in[32];
  const float* fc3b = (const float*)d_in[33];

  // ---- workspace carve. cnt|rblk|csr CONTIGUOUS (all sizes %256==0): ONE memset ----
  char* w = (char*)d_ws;
  size_t off = 0;
  auto alloc = [&](size_t bytes) -> void* {
    void* p = w + off;
    off += (bytes + 255) & ~(size_t)255;
    return p;
  };
  float* hbuf = (float*)alloc((size_t)B_ * 1268 * 64 * 4); // pooled features (max K1)
  float* xl   = (float*)alloc((size_t)NMAX * 256 * 4);     // source transform [N,256]
  float* xr   = (float*)alloc((size_t)NMAX * 256 * 4);     // target transform [N,256]
  float* nacc = (float*)alloc((size_t)NMAX * 64 * 4);      // fused GAT output (pre-pool)
  int*   cnt  = (int*)alloc((size_t)NMAX * 4);             // CSR degree counters
  char*  rblk = (char*)alloc(3 * 32 * 128 * 4);            // per-layer [rsum][rmaxI] x3
  int*   csr  = (int*)alloc((size_t)NMAX * MAXDEG * 4);
  float* sbuf = (float*)alloc((size_t)NMAX * 4);
  int* src    = (int*)alloc((size_t)E_TOT * 4);
  int* dst    = (int*)alloc((size_t)E_TOT * 4);
  int* em     = (int*)alloc((size_t)E_TOT * 4);
  int* new_id = (int*)alloc((size_t)NMAX * 4);
  int* perm   = (int*)alloc((size_t)32 * 1268 * 4);

  // one-time zero of cnt + rblk + csr (csr zero => every slot is an in-bounds edge id
  // forever, enabling k_gat_fused's unconditional csr/srcv prefetch)
  size_t zbytes = (size_t)NMAX * 4 + 3 * 32 * 128 * 4 + (size_t)NMAX * MAXDEG * 4;
  hipMemsetAsync(cnt, 0, zbytes, stream);

  const int Ns[3]    = {50688, 40576, 32480};   // B*N0, B*K1, B*K2 (all %16==0)
  const int npers[3] = {1584, 1268, 1015};
  const int ks[3]    = {1268, 1015, 812};
  const int GAT_BLOCKS = 2048;                  // 8 XCD x 4 graphs x 64 blocks

  for (int l = 0; l < 3; ++l) {
    int N = Ns[l];
    const float* hin = (l == 0) ? x : hbuf;
    float* rsum = (float*)(rblk + l * 32 * 128 * 4);
    u32* rmaxI  = (u32*)(rblk + l * 32 * 128 * 4 + 32 * 64 * 4);
    if (l == 0)
      k_tre<<<TRE_TBLK + TRE_EBLK, 256, 0, stream>>>(hin, gWl[l], gbl[l], gWr[l], gbr[l],
                                                     xl, xr, ei, src, dst, em, cnt, csr);
    else
      k_transform_t<64><<<N / 16, 256, 0, stream>>>(hin, gWl[l], gbl[l], gWr[l], gbr[l], xl, xr);
    k_gat_fused<<<GAT_BLOCKS, 256, 0, stream>>>(src, cnt, csr, ea, gWe[l], gatt[l],
                                                xl, xr, gb[l], pw[l], nacc, sbuf, npers[l]);
    k_topk<<<32, 1024, 0, stream>>>(sbuf, npers[l], ks[l], perm, new_id, cnt);
    int grows = CDIV(ks[l], 4);
    dim3 pgrid(32, grows + (l < 2 ? REMAP_Y : 0));
    k_post<<<pgrid, 256, 0, stream>>>(nacc, sbuf, perm, hbuf, ks[l], grows, rsum, rmaxI,
                                      src, dst, em, new_id, cnt, csr, (l < 2) ? 1 : 0);
  }
  k_mlp<<<32, 64, 0, stream>>>(rblk, fc1W, fc1b, fc2W, fc2b, fc3W, fc3b, (float*)d_out);
}

// Round 16
// 460.371 us; speedup vs baseline: 1.7473x; 1.0229x over previous
//
#include <hip/hip_runtime.h>

typedef unsigned short u16;
typedef unsigned int u32;
typedef unsigned long long u64;

#define E_TOT 202752   // B*N0*DEG = 32*1584*4
#define NMAX  50688    // B*N0
#define HEADS 4
#define B_    32
#define MAXDEG 32      // Poisson(4) in-degree: P(>=32) ~ 1e-18/node — safe bucket
#define REMAP_Y 25     // CDIV(E_TOT, 32*256)
#define TRE_TBLK 3168  // transform blocks for L0 = NMAX/16
#define TRE_EBLK 792   // edge-init blocks = CDIV(E_TOT,256)

#define CDIV(a,b) (((a)+(b)-1)/(b))

// order-preserving float->uint map (monotonic); code 0 is below any real float's code
__device__ __forceinline__ u32 ford(float f) {
  u32 u = __float_as_uint(f);
  return (u & 0x80000000u) ? ~u : (u | 0x80000000u);
}
__device__ __forceinline__ float ford_inv(u32 u) {
  u32 b = (u & 0x80000000u) ? (u ^ 0x80000000u) : ~u;
  return __uint_as_float(b);
}

// DPP row-rotate (16-lane row) move; CTRL = 0x120 | n for row_ror:n
template <int CTRL>
__device__ __forceinline__ float dpp_mov(float x) {
  return __int_as_float(__builtin_amdgcn_mov_dpp(__float_as_int(x), CTRL, 0xF, 0xF, false));
}
// sum over each 16-lane row via VALU-pipe rotations (no DS pipe on the hot path)
__device__ __forceinline__ float row16_sum(float v) {
  v += dpp_mov<0x121>(v);   // row_ror:1
  v += dpp_mov<0x122>(v);   // row_ror:2
  v += dpp_mov<0x124>(v);   // row_ror:4
  v += dpp_mov<0x128>(v);   // row_ror:8
  return v;
}

__device__ __forceinline__ u64 shfl_xor_u64(u64 v, int mask) {
  int lo = __shfl_xor((int)(u32)(v & 0xFFFFFFFFu), mask, 64);
  int hi = __shfl_xor((int)(u32)(v >> 32), mask, 64);
  return ((u64)(u32)hi << 32) | (u32)lo;
}

// ---------- FUSED: node transform L0 (FIN=32) + edge-array/CSR init in ONE launch.
// Measured R15: part of the 477.8->470.9 win. Blocks [0,TRE_TBLK): transform;
// blocks [TRE_TBLK,+TRE_EBLK): edge init. Fully independent roles, width preserved.
__global__ void k_tre(const float* __restrict__ hin,
                      const float* __restrict__ Wl, const float* __restrict__ bl,
                      const float* __restrict__ Wr, const float* __restrict__ br,
                      float* __restrict__ xl, float* __restrict__ xr,
                      const int* __restrict__ ei, int* __restrict__ src,
                      int* __restrict__ dst, int* __restrict__ em,
                      int* __restrict__ cnt, int* __restrict__ csr) {
  __shared__ float xs[32][20];
  int j = threadIdx.x;
  if (blockIdx.x >= TRE_TBLK) {          // ---- edge-init role ----
    int e = (blockIdx.x - TRE_TBLK) * 256 + j;
    if (e >= E_TOT) return;
    int s = ei[e], d = ei[E_TOT + e];
    src[e] = s;
    dst[e] = d;
    em[e] = 1;
    int pos = atomicAdd(&cnt[d], 1);
    if (pos < MAXDEG) csr[d * MAXDEG + pos] = e;
    return;
  }
  // ---- transform role (verified k_transform_t<32> body) ----
  int n0 = blockIdx.x * 16;
  for (int t = j; t < 16 * 32; t += 256) {
    int nd = t >> 5, f = t & 31;
    xs[f][nd] = hin[(size_t)(n0 + nd) * 32 + f];
  }
  __syncthreads();
  float al[16], ar[16];
  float blv = bl[j], brv = br[j];
#pragma unroll
  for (int t = 0; t < 16; ++t) { al[t] = blv; ar[t] = brv; }
  for (int i = 0; i < 32; ++i) {
    float wl = Wl[i * 256 + j], wr = Wr[i * 256 + j];
    float4 x0 = *(const float4*)&xs[i][0];
    float4 x1 = *(const float4*)&xs[i][4];
    float4 x2 = *(const float4*)&xs[i][8];
    float4 x3 = *(const float4*)&xs[i][12];
    al[0]  += x0.x * wl; ar[0]  += x0.x * wr;
    al[1]  += x0.y * wl; ar[1]  += x0.y * wr;
    al[2]  += x0.z * wl; ar[2]  += x0.z * wr;
    al[3]  += x0.w * wl; ar[3]  += x0.w * wr;
    al[4]  += x1.x * wl; ar[4]  += x1.x * wr;
    al[5]  += x1.y * wl; ar[5]  += x1.y * wr;
    al[6]  += x1.z * wl; ar[6]  += x1.z * wr;
    al[7]  += x1.w * wl; ar[7]  += x1.w * wr;
    al[8]  += x2.x * wl; ar[8]  += x2.x * wr;
    al[9]  += x2.y * wl; ar[9]  += x2.y * wr;
    al[10] += x2.z * wl; ar[10] += x2.z * wr;
    al[11] += x2.w * wl; ar[11] += x2.w * wr;
    al[12] += x3.x * wl; ar[12] += x3.x * wr;
    al[13] += x3.y * wl; ar[13] += x3.y * wr;
    al[14] += x3.z * wl; ar[14] += x3.z * wr;
    al[15] += x3.w * wl; ar[15] += x3.w * wr;
  }
#pragma unroll
  for (int t = 0; t < 16; ++t) {
    xl[(size_t)(n0 + t) * 256 + j] = al[t];
    xr[(size_t)(n0 + t) * 256 + j] = ar[t];
  }
}

// ---------- node transform for layers 1,2 (FIN=64) — unchanged verified version ----
template <int FIN>
__global__ void k_transform_t(const float* __restrict__ hin,
                              const float* __restrict__ Wl, const float* __restrict__ bl,
                              const float* __restrict__ Wr, const float* __restrict__ br,
                              float* __restrict__ xl, float* __restrict__ xr) {
  __shared__ float xs[FIN][20];
  int n0 = blockIdx.x * 16, j = threadIdx.x;   // 256 threads
  for (int t = j; t < 16 * FIN; t += 256) {
    int nd = t >> (FIN == 32 ? 5 : 6), f = t & (FIN - 1);
    xs[f][nd] = hin[(size_t)(n0 + nd) * FIN + f];
  }
  __syncthreads();
  float al[16], ar[16];
  float blv = bl[j], brv = br[j];
#pragma unroll
  for (int t = 0; t < 16; ++t) { al[t] = blv; ar[t] = brv; }
  for (int i = 0; i < FIN; ++i) {
    float wl = Wl[i * 256 + j], wr = Wr[i * 256 + j];
    float4 x0 = *(const float4*)&xs[i][0];     // broadcast b128 reads
    float4 x1 = *(const float4*)&xs[i][4];
    float4 x2 = *(const float4*)&xs[i][8];
    float4 x3 = *(const float4*)&xs[i][12];
    al[0]  += x0.x * wl; ar[0]  += x0.x * wr;
    al[1]  += x0.y * wl; ar[1]  += x0.y * wr;
    al[2]  += x0.z * wl; ar[2]  += x0.z * wr;
    al[3]  += x0.w * wl; ar[3]  += x0.w * wr;
    al[4]  += x1.x * wl; ar[4]  += x1.x * wr;
    al[5]  += x1.y * wl; ar[5]  += x1.y * wr;
    al[6]  += x1.z * wl; ar[6]  += x1.z * wr;
    al[7]  += x1.w * wl; ar[7]  += x1.w * wr;
    al[8]  += x2.x * wl; ar[8]  += x2.x * wr;
    al[9]  += x2.y * wl; ar[9]  += x2.y * wr;
    al[10] += x2.z * wl; ar[10] += x2.z * wr;
    al[11] += x2.w * wl; ar[11] += x2.w * wr;
    al[12] += x3.x * wl; ar[12] += x3.x * wr;
    al[13] += x3.y * wl; ar[13] += x3.y * wr;
    al[14] += x3.z * wl; ar[14] += x3.z * wr;
    al[15] += x3.w * wl; ar[15] += x3.w * wr;
  }
#pragma unroll
  for (int t = 0; t < 16; ++t) {
    xl[(size_t)(n0 + t) * 256 + j] = al[t];
    xr[(size_t)(n0 + t) * 256 + j] = ar[t];
  }
}

// ---------- fused GATv2 — EXACT R6-verified version (66-67us L0, FETCH 78MB,
// WRITE 13MB, VALUBusy 48%, 56 VGPR, zero spill). Prefetch variants failed twice:
// R11 (hard 64-VGPR cap) and R15 (allocator spilled despite launch_bounds headroom,
// WRITE 13->24MB, +3.5us). This kernel is register-bound at its sweet spot — do not
// add live state.
__global__ void k_gat_fused(const int* __restrict__ srcv, const int* __restrict__ cnt,
                            const int* __restrict__ csr, const float* __restrict__ ea,
                            const float* __restrict__ We, const float* __restrict__ att,
                            const float* __restrict__ xl, const float* __restrict__ xr,
                            const float* __restrict__ bias, const float* __restrict__ pwv,
                            float* __restrict__ out, float* __restrict__ sc,
                            int n_per) {
  int b = blockIdx.x;
  int xcd = b & 7;
  int jj = b >> 3;                                 // 0..255 within XCD
  int g = xcd + 8 * (jj >> 6);                     // graph 0..31, g%8 == xcd
  int wv = ((jj & 63) << 2) + (threadIdx.x >> 6);  // wave-in-graph 0..255
  int lane = threadIdx.x & 63;
  int cg = lane & 15;
  int cb = (lane >> 4) * 64 + cg * 4;              // this lane's 4 channels
  int npw = CDIV(n_per, 256);
  int l0 = wv * npw, l1 = min(n_per, l0 + npw);
  if (l0 >= n_per) return;
  int n0 = g * n_per + l0, n1 = g * n_per + l1;
  // per-layer constants, hoisted once per wave
  float4 at4 = *(const float4*)(att + cb);
  float4 w0 = *(const float4*)(We + 0 * 256 + cb);
  float4 w1 = *(const float4*)(We + 1 * 256 + cb);
  float4 w2 = *(const float4*)(We + 2 * 256 + cb);
  float4 w3 = *(const float4*)(We + 3 * 256 + cb);
  float4 w4_ = *(const float4*)(We + 4 * 256 + cb);
  float4 w5 = *(const float4*)(We + 5 * 256 + cb);
  float4 w6 = *(const float4*)(We + 6 * 256 + cb);
  float4 w7 = *(const float4*)(We + 7 * 256 + cb);
  float4 bi4 = *(const float4*)(bias + cg * 4);
  float4 pw4 = *(const float4*)(pwv + cg * 4);
  float wn = pw4.x * pw4.x + pw4.y * pw4.y + pw4.z * pw4.z + pw4.w * pw4.w;
  wn += __shfl_xor(wn, 1, 64); wn += __shfl_xor(wn, 2, 64);
  wn += __shfl_xor(wn, 4, 64); wn += __shfl_xor(wn, 8, 64);
  float isq = 1.f / sqrtf(wn);

  // pipeline prologue: first node's metadata + xr row in flight
  int degc = cnt[n0];
  int e_c = (lane < MAXDEG) ? csr[n0 * MAXDEG + lane] : 0;
  int s_c = srcv[e_c];                            // garbage beyond deg: masked later
  float4 xdc = *(const float4*)(xr + (size_t)n0 * 256 + cb);

  for (int n = n0; n < n1; ++n) {
    // issue NEXT node's loads first: they drain while we compute this node
    int degn = 0, e_n = 0, s_n = 0;
    float4 xdn = xdc;
    if (n + 1 < n1) {
      degn = cnt[n + 1];
      e_n = (lane < MAXDEG) ? csr[(n + 1) * MAXDEG + lane] : 0;
      s_n = srcv[e_n];
      xdn = *(const float4*)(xr + (size_t)(n + 1) * 256 + cb);
    }
    int deg = min(degc, MAXDEG);
    int e_l = e_c, s_l = s_c;
    float4 xd4 = xdc;
    float m = -INFINITY, l = 0.f;
    float ox = 0.f, oy = 0.f, oz = 0.f, ow = 0.f;
    for (int i0 = 0; i0 < deg; i0 += 4) {
      int c0 = deg - i0; if (c0 > 4) c0 = 4;       // wave-uniform
      float4 xs[4], a0[4], a1[4];
#pragma unroll
      for (int j = 0; j < 4; ++j) {
        int idx = (j < c0) ? (i0 + j) : i0;        // clamp to a safe slot (uniform)
        int e = __builtin_amdgcn_readlane(e_l, idx);   // VALU->SGPR broadcast
        int s = __builtin_amdgcn_readlane(s_l, idx);
        xs[j] = *(const float4*)(xl + (size_t)s * 256 + cb);   // independent, in flight
        a0[j] = *(const float4*)(ea + (size_t)e * 8);
        a1[j] = *(const float4*)(ea + (size_t)e * 8 + 4);
      }
      // --- logits for the whole chunk, fully independent across j ---
      float v[4];
#pragma unroll
      for (int j = 0; j < 4; ++j) {
        if (j < c0) {
          float e0 = a0[j].x * w0.x + a0[j].y * w1.x + a0[j].z * w2.x + a0[j].w * w3.x
                   + a1[j].x * w4_.x + a1[j].y * w5.x + a1[j].z * w6.x + a1[j].w * w7.x;
          float e1 = a0[j].x * w0.y + a0[j].y * w1.y + a0[j].z * w2.y + a0[j].w * w3.y
                   + a1[j].x * w4_.y + a1[j].y * w5.y + a1[j].z * w6.y + a1[j].w * w7.y;
          float e2 = a0[j].x * w0.z + a0[j].y * w1.z + a0[j].z * w2.z + a0[j].w * w3.z
                   + a1[j].x * w4_.z + a1[j].y * w5.z + a1[j].z * w6.z + a1[j].w * w7.z;
          float e3 = a0[j].x * w0.w + a0[j].y * w1.w + a0[j].z * w2.w + a0[j].w * w3.w
                   + a1[j].x * w4_.w + a1[j].y * w5.w + a1[j].z * w6.w + a1[j].w * w7.w;
          float m0 = xs[j].x + xd4.x + e0; m0 = (m0 >= 0.f) ? m0 : 0.2f * m0;  // leaky
          float m1 = xs[j].y + xd4.y + e1; m1 = (m1 >= 0.f) ? m1 : 0.2f * m1;
          float m2 = xs[j].z + xd4.z + e2; m2 = (m2 >= 0.f) ? m2 : 0.2f * m2;
          float m3 = xs[j].w + xd4.w + e3; m3 = (m3 >= 0.f) ? m3 : 0.2f * m3;
          float d = at4.x * m0 + at4.y * m1 + at4.z * m2 + at4.w * m3;
          v[j] = row16_sum(d);           // 4 independent DPP chains interleave on VALU
        } else {
          v[j] = -INFINITY;              // pad slot: p=exp(-inf-nm)=0, no contribution
        }
      }
      // --- ONE max + rescale for the whole chunk ---
      float vm = fmaxf(fmaxf(v[0], v[1]), fmaxf(v[2], v[3]));
      float nm = fmaxf(m, vm);
      float scale = __expf(m - nm);      // first chunk: m=-inf -> scale=0
      float p0 = __expf(v[0] - nm), p1 = __expf(v[1] - nm);
      float p2 = __expf(v[2] - nm), p3 = __expf(v[3] - nm);
      ox = ox * scale + ((p0 * xs[0].x + p1 * xs[1].x) + (p2 * xs[2].x + p3 * xs[3].x));
      oy = oy * scale + ((p0 * xs[0].y + p1 * xs[1].y) + (p2 * xs[2].y + p3 * xs[3].y));
      oz = oz * scale + ((p0 * xs[0].z + p1 * xs[1].z) + (p2 * xs[2].z + p3 * xs[3].z));
      ow = ow * scale + ((p0 * xs[0].w + p1 * xs[1].w) + (p2 * xs[2].w + p3 * xs[3].w));
      l = l * scale + ((p0 + p1) + (p2 + p3));
      m = nm;
    }
    // per-head y = O/den, then 0.25 * head-sum  (deg==0 -> l=0 -> y=0, matches ref)
    float inv = 0.25f / fmaxf(l, 1e-16f);
    float r0 = ox * inv, r1 = oy * inv, r2 = oz * inv, r3 = ow * inv;
    r0 += __shfl_xor(r0, 16, 64); r0 += __shfl_xor(r0, 32, 64);
    r1 += __shfl_xor(r1, 16, 64); r1 += __shfl_xor(r1, 32, 64);
    r2 += __shfl_xor(r2, 16, 64); r2 += __shfl_xor(r2, 32, 64);
    r3 += __shfl_xor(r3, 16, 64); r3 += __shfl_xor(r3, 32, 64);
    float rr0 = fmaxf(r0 + bi4.x, 0.f), rr1 = fmaxf(r1 + bi4.y, 0.f);
    float rr2 = fmaxf(r2 + bi4.z, 0.f), rr3 = fmaxf(r3 + bi4.w, 0.f);
    if (lane < 16) *(float4*)(out + (size_t)n * 64 + cg * 4) = float4{rr0, rr1, rr2, rr3};
    // topk score: s = tanh(h.w / ||w||)
    float dot = rr0 * pw4.x + rr1 * pw4.y + rr2 * pw4.z + rr3 * pw4.w;
    dot += __shfl_xor(dot, 1, 64);
    dot += __shfl_xor(dot, 2, 64);
    dot += __shfl_xor(dot, 4, 64);
    dot += __shfl_xor(dot, 8, 64);
    if (lane == 0) sc[n] = tanhf(dot * isq);
    // rotate pipeline registers
    degc = degn; e_c = e_n; s_c = s_n; xdc = xdn;
  }
}

// stable descending top-k per graph — u64 keys (ford(score)<<32 | ~idx).
// Hybrid bitonic over 2048 elements, 2 elements/thread in registers (measured R6).
// Also zeroes cnt[0, B*k) for the next layer (replaces a hipMemsetAsync).
__global__ __launch_bounds__(1024) void k_topk(const float* __restrict__ s, int n_per,
                                               int k,
                                               int* __restrict__ perm, int* __restrict__ new_id,
                                               int* __restrict__ cnt) {
  __shared__ u64 kv[2048];
  int b = blockIdx.x, t = threadIdx.x;
  int base = b * n_per;
  for (int i = t; i < n_per; i += 1024) new_id[base + i] = -1;
  for (int i = t; i < k; i += 1024) cnt[b * k + i] = 0;   // next layer's CSR counters

  u64 e0, e1;
  {
    u32 sk0 = (t < n_per) ? ford(s[base + t]) : 0u;             // pad key 0: below all
    int i1 = t + 1024;
    u32 sk1 = (i1 < n_per) ? ford(s[base + i1]) : 0u;
    e0 = ((u64)sk0 << 32) | (u32)(0xFFFFFFFFu - (u32)t);        // tie -> lower idx first
    e1 = ((u64)sk1 << 32) | (u32)(0xFFFFFFFFu - (u32)i1);
  }

  for (int kk = 2; kk <= 2048; kk <<= 1) {
    int j = kk >> 1;
    if (j == 1024) {                     // partner of element t is element t+1024: local
      u64 mx = e0 > e1 ? e0 : e1;
      u64 mn = e0 > e1 ? e1 : e0;
      e0 = mx; e1 = mn;
      j >>= 1;
    }
    for (; j >= 64; j >>= 1) {           // cross-wave: LDS exchange
      __syncthreads();                   // prior pass's reads complete before overwrite
      kv[t] = e0; kv[t + 1024] = e1;
      __syncthreads();
      u64 p0 = kv[t ^ j], p1 = kv[(t + 1024) ^ j];
      int i1 = t + 1024;
      bool km0 = (((t  & kk) == 0) == ((t  & j) == 0));
      bool km1 = (((i1 & kk) == 0) == ((i1 & j) == 0));
      e0 = km0 ? (e0 > p0 ? e0 : p0) : (e0 < p0 ? e0 : p0);
      e1 = km1 ? (e1 > p1 ? e1 : p1) : (e1 < p1 ? e1 : p1);
    }
    for (; j >= 1; j >>= 1) {            // intra-wave: shuffle exchange, no barriers
      u64 p0 = shfl_xor_u64(e0, j);
      u64 p1 = shfl_xor_u64(e1, j);
      int i1 = t + 1024;
      bool km0 = (((t  & kk) == 0) == ((t  & j) == 0));
      bool km1 = (((i1 & kk) == 0) == ((i1 & j) == 0));
      e0 = km0 ? (e0 > p0 ? e0 : p0) : (e0 < p0 ? e0 : p0);
      e1 = km1 ? (e1 > p1 ? e1 : p1) : (e1 < p1 ? e1 : p1);
    }
  }

  // element i holds rank i (descending): e0 = rank t, e1 = rank t+1024
  if (t < k) {
    int old0 = (int)(0xFFFFFFFFu - (u32)(e0 & 0xFFFFFFFFu));
    perm[b * k + t] = base + old0;
    new_id[base + old0] = b * k + t;
  }
  int r1 = t + 1024;
  if (r1 < k) {
    int old1 = (int)(0xFFFFFFFFu - (u32)(e1 & 0xFFFFFFFFu));
    perm[b * k + r1] = base + old1;
    new_id[base + old1] = b * k + r1;
  }
}

// fused post-pool: WIDE gather+readout AND edge remap in ONE launch (measured good;
// R10 narrow fusion and R12 spin fusion both regressed — width matters).
// grid: dim3(32, gather_rows [+ REMAP_Y when do_remap]).
__global__ void k_post(const float* __restrict__ hin, const float* __restrict__ s,
                       const int* __restrict__ perm, float* __restrict__ hout,
                       int k, int gather_rows,
                       float* __restrict__ rsum, u32* __restrict__ rmaxI,
                       int* __restrict__ src, int* __restrict__ dst, int* __restrict__ em,
                       const int* __restrict__ new_id, int* __restrict__ cnt,
                       int* __restrict__ csr, int do_remap) {
  __shared__ float ps[256], pm[256];
  int b = blockIdx.x, yy = blockIdx.y, t = threadIdx.x;
  if (yy < gather_rows) {
    int i = yy * 4 + (t >> 6);            // local kept-node index
    int c = t & 63;
    bool valid = i < k;
    float v = 0.f;
    if (valid) {
      int g = perm[b * k + i];
      v = hin[(size_t)g * 64 + c] * s[g];
      hout[((size_t)b * k + i) * 64 + c] = v;
    }
    ps[t] = valid ? v : 0.f;
    pm[t] = valid ? v : -INFINITY;
    __syncthreads();
    if (t < 64) {
      float s4 = ps[t] + ps[t + 64] + ps[t + 128] + ps[t + 192];
      float m4 = fmaxf(fmaxf(pm[t], pm[t + 64]), fmaxf(pm[t + 128], pm[t + 192]));
      atomicAdd(&rsum[b * 64 + t], s4);
      atomicMax(&rmaxI[b * 64 + t], ford(m4));
    }
  } else if (do_remap) {
    int e = ((yy - gather_rows) * 32 + b) * 256 + t;
    if (e < E_TOT) {
      int ns = new_id[src[e]], nd = new_id[dst[e]];
      int mm = em[e] && ns >= 0 && nd >= 0;
      src[e] = mm ? ns : 0;
      dst[e] = mm ? nd : 0;
      em[e] = mm;
      if (mm) {
        int pos = atomicAdd(&cnt[nd], 1);
        if (pos < MAXDEG) csr[nd * MAXDEG + pos] = e;
      }
    }
  }
}

// MLP with readout finalization folded in: reads [rsum|rmaxI] x 3 layers directly
__global__ void k_mlp(const char* __restrict__ rblk,
                      const float* __restrict__ W1, const float* __restrict__ b1,
                      const float* __restrict__ W2, const float* __restrict__ b2,
                      const float* __restrict__ W3, const float* __restrict__ b3,
                      float* __restrict__ out) {
  __shared__ float v0[128], v1[64], v2[64], lgts[16];
  int b = blockIdx.x, t = threadIdx.x;   // 64 threads
  const float* rs0 = (const float*)rblk;
  const u32*   rm0 = (const u32*)(rblk + 32 * 64 * 4);
  const float* rs1 = (const float*)(rblk + 32 * 128 * 4);
  const u32*   rm1 = (const u32*)(rblk + 32 * 128 * 4 + 32 * 64 * 4);
  const float* rs2 = (const float*)(rblk + 2 * 32 * 128 * 4);
  const u32*   rm2 = (const u32*)(rblk + 2 * 32 * 128 * 4 + 32 * 64 * 4);
  v0[t] = rs0[b * 64 + t] / 1268.f + rs1[b * 64 + t] / 1015.f + rs2[b * 64 + t] / 812.f;
  v0[64 + t] = ford_inv(rm0[b * 64 + t]) + ford_inv(rm1[b * 64 + t]) + ford_inv(rm2[b * 64 + t]);
  __syncthreads();
  float a = b1[t];
  for (int i = 0; i < 128; ++i) a += v0[i] * W1[i * 64 + t];
  v1[t] = fmaxf(a, 0.f);
  __syncthreads();
  a = b2[t];
  for (int i = 0; i < 64; ++i) a += v1[i] * W2[i * 64 + t];
  v2[t] = fmaxf(a, 0.f);
  __syncthreads();
  if (t < 16) {
    a = b3[t];
    for (int i = 0; i < 64; ++i) a += v2[i] * W3[i * 16 + t];
    lgts[t] = a;
  }
  __syncthreads();
  if (t == 0) {
    float m = lgts[0];
    for (int j = 1; j < 16; ++j) m = fmaxf(m, lgts[j]);
    float ex[16], sum = 0.f;
    for (int j = 0; j < 16; ++j) { ex[j] = expf(lgts[j] - m); sum += ex[j]; }
    for (int j = 0; j < 16; ++j) out[b * 16 + j] = ex[j] / sum;
  }
}

extern "C" void kernel_launch(void* const* d_in, const int* in_sizes, int n_in,
                              void* d_out, int out_size, void* d_ws, size_t ws_size,
                              hipStream_t stream) {
  (void)in_sizes; (void)n_in; (void)out_size; (void)ws_size;
  const float* x  = (const float*)d_in[0];      // [NMAX, 32] f32
  const float* ea = (const float*)d_in[1];      // [E, 8]     f32
  const int*   ei = (const int*)d_in[2];        // [2, E]

  const float *gWl[3], *gbl[3], *gWr[3], *gbr[3], *gWe[3], *gatt[3], *gb[3], *pw[3];
  for (int l = 0; l < 3; ++l) {
    int p0 = 4 + 7 * l;
    gWl[l]  = (const float*)d_in[p0 + 0];
    gbl[l]  = (const float*)d_in[p0 + 1];
    gWr[l]  = (const float*)d_in[p0 + 2];
    gbr[l]  = (const float*)d_in[p0 + 3];
    gWe[l]  = (const float*)d_in[p0 + 4];
    gatt[l] = (const float*)d_in[p0 + 5];
    gb[l]   = (const float*)d_in[p0 + 6];
    pw[l]   = (const float*)d_in[25 + l];
  }
  const float* fc1W = (const float*)d_in[28];
  const float* fc1b = (const float*)d_in[29];
  const float* fc2W = (const float*)d_in[30];
  const float* fc2b = (const float*)d_in[31];
  const float* fc3W = (const float*)d_in[32];
  const float* fc3b = (const float*)d_in[33];

  // ---- workspace carve. cnt|rblk|csr CONTIGUOUS (all sizes %256==0): ONE memset ----
  char* w = (char*)d_ws;
  size_t off = 0;
  auto alloc = [&](size_t bytes) -> void* {
    void* p = w + off;
    off += (bytes + 255) & ~(size_t)255;
    return p;
  };
  float* hbuf = (float*)alloc((size_t)B_ * 1268 * 64 * 4); // pooled features (max K1)
  float* xl   = (float*)alloc((size_t)NMAX * 256 * 4);     // source transform [N,256]
  float* xr   = (float*)alloc((size_t)NMAX * 256 * 4);     // target transform [N,256]
  float* nacc = (float*)alloc((size_t)NMAX * 64 * 4);      // fused GAT output (pre-pool)
  int*   cnt  = (int*)alloc((size_t)NMAX * 4);             // CSR degree counters
  char*  rblk = (char*)alloc(3 * 32 * 128 * 4);            // per-layer [rsum][rmaxI] x3
  int*   csr  = (int*)alloc((size_t)NMAX * MAXDEG * 4);
  float* sbuf = (float*)alloc((size_t)NMAX * 4);
  int* src    = (int*)alloc((size_t)E_TOT * 4);
  int* dst    = (int*)alloc((size_t)E_TOT * 4);
  int* em     = (int*)alloc((size_t)E_TOT * 4);
  int* new_id = (int*)alloc((size_t)NMAX * 4);
  int* perm   = (int*)alloc((size_t)32 * 1268 * 4);

  // one-time zero of cnt + rblk + csr (csr zero => every slot is an in-bounds edge id
  // forever, enabling k_gat_fused's unconditional csr/srcv prefetch)
  size_t zbytes = (size_t)NMAX * 4 + 3 * 32 * 128 * 4 + (size_t)NMAX * MAXDEG * 4;
  hipMemsetAsync(cnt, 0, zbytes, stream);

  const int Ns[3]    = {50688, 40576, 32480};   // B*N0, B*K1, B*K2 (all %16==0)
  const int npers[3] = {1584, 1268, 1015};
  const int ks[3]    = {1268, 1015, 812};
  const int GAT_BLOCKS = 2048;                  // 8 XCD x 4 graphs x 64 blocks

  for (int l = 0; l < 3; ++l) {
    int N = Ns[l];
    const float* hin = (l == 0) ? x : hbuf;
    float* rsum = (float*)(rblk + l * 32 * 128 * 4);
    u32* rmaxI  = (u32*)(rblk + l * 32 * 128 * 4 + 32 * 64 * 4);
    if (l == 0)
      k_tre<<<TRE_TBLK + TRE_EBLK, 256, 0, stream>>>(hin, gWl[l], gbl[l], gWr[l], gbr[l],
                                                     xl, xr, ei, src, dst, em, cnt, csr);
    else
      k_transform_t<64><<<N / 16, 256, 0, stream>>>(hin, gWl[l], gbl[l], gWr[l], gbr[l], xl, xr);
    k_gat_fused<<<GAT_BLOCKS, 256, 0, stream>>>(src, cnt, csr, ea, gWe[l], gatt[l],
                                                xl, xr, gb[l], pw[l], nacc, sbuf, npers[l]);
    k_topk<<<32, 1024, 0, stream>>>(sbuf, npers[l], ks[l], perm, new_id, cnt);
    int grows = CDIV(ks[l], 4);
    dim3 pgrid(32, grows + (l < 2 ? REMAP_Y : 0));
    k_post<<<pgrid, 256, 0, stream>>>(nacc, sbuf, perm, hbuf, ks[l], grows, rsum, rmaxI,
                                      src, dst, em, new_id, cnt, csr, (l < 2) ? 1 : 0);
  }
  k_mlp<<<32, 64, 0, stream>>>(rblk, fc1W, fc1b, fc2W, fc2b, fc3W, fc3b, (float*)d_out);
}

// Round 17
// 456.423 us; speedup vs baseline: 1.7624x; 1.0086x over previous
//
#include <hip/hip_runtime.h>

typedef unsigned short u16;
typedef unsigned int u32;
typedef unsigned long long u64;

#define E_TOT 202752   // B*N0*DEG = 32*1584*4
#define NMAX  50688    // B*N0
#define HEADS 4
#define B_    32
#define MAXDEG 32      // Poisson(4) in-degree: P(>=32) ~ 1e-18/node — safe bucket
#define REMAP_Y 25     // CDIV(E_TOT, 32*256)
#define TRE_TBLK 3168  // transform blocks for L0 = NMAX/16
#define TRE_EBLK 792   // edge-init blocks = CDIV(E_TOT,256)

#define CDIV(a,b) (((a)+(b)-1)/(b))

// order-preserving float->uint map (monotonic); code 0 is below any real float's code
__device__ __forceinline__ u32 ford(float f) {
  u32 u = __float_as_uint(f);
  return (u & 0x80000000u) ? ~u : (u | 0x80000000u);
}
__device__ __forceinline__ float ford_inv(u32 u) {
  u32 b = (u & 0x80000000u) ? (u ^ 0x80000000u) : ~u;
  return __uint_as_float(b);
}

// DPP row-rotate (16-lane row) move; CTRL = 0x120 | n for row_ror:n
template <int CTRL>
__device__ __forceinline__ float dpp_mov(float x) {
  return __int_as_float(__builtin_amdgcn_mov_dpp(__float_as_int(x), CTRL, 0xF, 0xF, false));
}
// sum over each 16-lane row via VALU-pipe rotations (no DS pipe on the hot path)
__device__ __forceinline__ float row16_sum(float v) {
  v += dpp_mov<0x121>(v);   // row_ror:1
  v += dpp_mov<0x122>(v);   // row_ror:2
  v += dpp_mov<0x124>(v);   // row_ror:4
  v += dpp_mov<0x128>(v);   // row_ror:8
  return v;
}

__device__ __forceinline__ u64 shfl_xor_u64(u64 v, int mask) {
  int lo = __shfl_xor((int)(u32)(v & 0xFFFFFFFFu), mask, 64);
  int hi = __shfl_xor((int)(u32)(v >> 32), mask, 64);
  return ((u64)(u32)hi << 32) | (u32)lo;
}

// ---------- FUSED: node transform L0 (FIN=32) + edge-array/CSR init in ONE launch.
// Measured R15/R16: part of the 477.8->460.4 wins. Blocks [0,TRE_TBLK): transform;
// blocks [TRE_TBLK,+TRE_EBLK): edge init. Fully independent roles, width preserved.
__global__ void k_tre(const float* __restrict__ hin,
                      const float* __restrict__ Wl, const float* __restrict__ bl,
                      const float* __restrict__ Wr, const float* __restrict__ br,
                      float* __restrict__ xl, float* __restrict__ xr,
                      const int* __restrict__ ei, int* __restrict__ src,
                      int* __restrict__ dst, int* __restrict__ em,
                      int* __restrict__ cnt, int* __restrict__ csr) {
  __shared__ float xs[32][20];
  int j = threadIdx.x;
  if (blockIdx.x >= TRE_TBLK) {          // ---- edge-init role ----
    int e = (blockIdx.x - TRE_TBLK) * 256 + j;
    if (e >= E_TOT) return;
    int s = ei[e], d = ei[E_TOT + e];
    src[e] = s;
    dst[e] = d;
    em[e] = 1;
    int pos = atomicAdd(&cnt[d], 1);
    if (pos < MAXDEG) csr[d * MAXDEG + pos] = e;
    return;
  }
  // ---- transform role (verified k_transform_t<32> body) ----
  int n0 = blockIdx.x * 16;
  for (int t = j; t < 16 * 32; t += 256) {
    int nd = t >> 5, f = t & 31;
    xs[f][nd] = hin[(size_t)(n0 + nd) * 32 + f];
  }
  __syncthreads();
  float al[16], ar[16];
  float blv = bl[j], brv = br[j];
#pragma unroll
  for (int t = 0; t < 16; ++t) { al[t] = blv; ar[t] = brv; }
  for (int i = 0; i < 32; ++i) {
    float wl = Wl[i * 256 + j], wr = Wr[i * 256 + j];
    float4 x0 = *(const float4*)&xs[i][0];
    float4 x1 = *(const float4*)&xs[i][4];
    float4 x2 = *(const float4*)&xs[i][8];
    float4 x3 = *(const float4*)&xs[i][12];
    al[0]  += x0.x * wl; ar[0]  += x0.x * wr;
    al[1]  += x0.y * wl; ar[1]  += x0.y * wr;
    al[2]  += x0.z * wl; ar[2]  += x0.z * wr;
    al[3]  += x0.w * wl; ar[3]  += x0.w * wr;
    al[4]  += x1.x * wl; ar[4]  += x1.x * wr;
    al[5]  += x1.y * wl; ar[5]  += x1.y * wr;
    al[6]  += x1.z * wl; ar[6]  += x1.z * wr;
    al[7]  += x1.w * wl; ar[7]  += x1.w * wr;
    al[8]  += x2.x * wl; ar[8]  += x2.x * wr;
    al[9]  += x2.y * wl; ar[9]  += x2.y * wr;
    al[10] += x2.z * wl; ar[10] += x2.z * wr;
    al[11] += x2.w * wl; ar[11] += x2.w * wr;
    al[12] += x3.x * wl; ar[12] += x3.x * wr;
    al[13] += x3.y * wl; ar[13] += x3.y * wr;
    al[14] += x3.z * wl; ar[14] += x3.z * wr;
    al[15] += x3.w * wl; ar[15] += x3.w * wr;
  }
#pragma unroll
  for (int t = 0; t < 16; ++t) {
    xl[(size_t)(n0 + t) * 256 + j] = al[t];
    xr[(size_t)(n0 + t) * 256 + j] = ar[t];
  }
}

// ---------- node transform for layers 1,2 (FIN=64) — unchanged verified version ----
template <int FIN>
__global__ void k_transform_t(const float* __restrict__ hin,
                              const float* __restrict__ Wl, const float* __restrict__ bl,
                              const float* __restrict__ Wr, const float* __restrict__ br,
                              float* __restrict__ xl, float* __restrict__ xr) {
  __shared__ float xs[FIN][20];
  int n0 = blockIdx.x * 16, j = threadIdx.x;   // 256 threads
  for (int t = j; t < 16 * FIN; t += 256) {
    int nd = t >> (FIN == 32 ? 5 : 6), f = t & (FIN - 1);
    xs[f][nd] = hin[(size_t)(n0 + nd) * FIN + f];
  }
  __syncthreads();
  float al[16], ar[16];
  float blv = bl[j], brv = br[j];
#pragma unroll
  for (int t = 0; t < 16; ++t) { al[t] = blv; ar[t] = brv; }
  for (int i = 0; i < FIN; ++i) {
    float wl = Wl[i * 256 + j], wr = Wr[i * 256 + j];
    float4 x0 = *(const float4*)&xs[i][0];     // broadcast b128 reads
    float4 x1 = *(const float4*)&xs[i][4];
    float4 x2 = *(const float4*)&xs[i][8];
    float4 x3 = *(const float4*)&xs[i][12];
    al[0]  += x0.x * wl; ar[0]  += x0.x * wr;
    al[1]  += x0.y * wl; ar[1]  += x0.y * wr;
    al[2]  += x0.z * wl; ar[2]  += x0.z * wr;
    al[3]  += x0.w * wl; ar[3]  += x0.w * wr;
    al[4]  += x1.x * wl; ar[4]  += x1.x * wr;
    al[5]  += x1.y * wl; ar[5]  += x1.y * wr;
    al[6]  += x1.z * wl; ar[6]  += x1.z * wr;
    al[7]  += x1.w * wl; ar[7]  += x1.w * wr;
    al[8]  += x2.x * wl; ar[8]  += x2.x * wr;
    al[9]  += x2.y * wl; ar[9]  += x2.y * wr;
    al[10] += x2.z * wl; ar[10] += x2.z * wr;
    al[11] += x2.w * wl; ar[11] += x2.w * wr;
    al[12] += x3.x * wl; ar[12] += x3.x * wr;
    al[13] += x3.y * wl; ar[13] += x3.y * wr;
    al[14] += x3.z * wl; ar[14] += x3.z * wr;
    al[15] += x3.w * wl; ar[15] += x3.w * wr;
  }
#pragma unroll
  for (int t = 0; t < 16; ++t) {
    xl[(size_t)(n0 + t) * 256 + j] = al[t];
    xr[(size_t)(n0 + t) * 256 + j] = ar[t];
  }
}

// ---------- fused GATv2 — R6-verified math + s_setprio around per-chunk compute ----
// T5 experiment (zero registers, zero sync risk): waves here are fully independent
// (no barriers), alternating gather-wait <-> ~200-instr VALU burst — structurally the
// attn case where setprio measured +4-7% (vs lockstep GEMM where it was neutral/neg).
// setprio(1) after the chunk's gathers are issued, setprio(0) after its accumulate.
// Canaries: VGPR must stay 56, WRITE ~13MB, FETCH ~78MB.
__global__ void k_gat_fused(const int* __restrict__ srcv, const int* __restrict__ cnt,
                            const int* __restrict__ csr, const float* __restrict__ ea,
                            const float* __restrict__ We, const float* __restrict__ att,
                            const float* __restrict__ xl, const float* __restrict__ xr,
                            const float* __restrict__ bias, const float* __restrict__ pwv,
                            float* __restrict__ out, float* __restrict__ sc,
                            int n_per) {
  int b = blockIdx.x;
  int xcd = b & 7;
  int jj = b >> 3;                                 // 0..255 within XCD
  int g = xcd + 8 * (jj >> 6);                     // graph 0..31, g%8 == xcd
  int wv = ((jj & 63) << 2) + (threadIdx.x >> 6);  // wave-in-graph 0..255
  int lane = threadIdx.x & 63;
  int cg = lane & 15;
  int cb = (lane >> 4) * 64 + cg * 4;              // this lane's 4 channels
  int npw = CDIV(n_per, 256);
  int l0 = wv * npw, l1 = min(n_per, l0 + npw);
  if (l0 >= n_per) return;
  int n0 = g * n_per + l0, n1 = g * n_per + l1;
  // per-layer constants, hoisted once per wave
  float4 at4 = *(const float4*)(att + cb);
  float4 w0 = *(const float4*)(We + 0 * 256 + cb);
  float4 w1 = *(const float4*)(We + 1 * 256 + cb);
  float4 w2 = *(const float4*)(We + 2 * 256 + cb);
  float4 w3 = *(const float4*)(We + 3 * 256 + cb);
  float4 w4_ = *(const float4*)(We + 4 * 256 + cb);
  float4 w5 = *(const float4*)(We + 5 * 256 + cb);
  float4 w6 = *(const float4*)(We + 6 * 256 + cb);
  float4 w7 = *(const float4*)(We + 7 * 256 + cb);
  float4 bi4 = *(const float4*)(bias + cg * 4);
  float4 pw4 = *(const float4*)(pwv + cg * 4);
  float wn = pw4.x * pw4.x + pw4.y * pw4.y + pw4.z * pw4.z + pw4.w * pw4.w;
  wn += __shfl_xor(wn, 1, 64); wn += __shfl_xor(wn, 2, 64);
  wn += __shfl_xor(wn, 4, 64); wn += __shfl_xor(wn, 8, 64);
  float isq = 1.f / sqrtf(wn);

  // pipeline prologue: first node's metadata + xr row in flight
  int degc = cnt[n0];
  int e_c = (lane < MAXDEG) ? csr[n0 * MAXDEG + lane] : 0;
  int s_c = srcv[e_c];                            // garbage beyond deg: masked later
  float4 xdc = *(const float4*)(xr + (size_t)n0 * 256 + cb);

  for (int n = n0; n < n1; ++n) {
    // issue NEXT node's loads first: they drain while we compute this node
    int degn = 0, e_n = 0, s_n = 0;
    float4 xdn = xdc;
    if (n + 1 < n1) {
      degn = cnt[n + 1];
      e_n = (lane < MAXDEG) ? csr[(n + 1) * MAXDEG + lane] : 0;
      s_n = srcv[e_n];
      xdn = *(const float4*)(xr + (size_t)(n + 1) * 256 + cb);
    }
    int deg = min(degc, MAXDEG);
    int e_l = e_c, s_l = s_c;
    float4 xd4 = xdc;
    float m = -INFINITY, l = 0.f;
    float ox = 0.f, oy = 0.f, oz = 0.f, ow = 0.f;
    for (int i0 = 0; i0 < deg; i0 += 4) {
      int c0 = deg - i0; if (c0 > 4) c0 = 4;       // wave-uniform
      float4 xs[4], a0[4], a1[4];
#pragma unroll
      for (int j = 0; j < 4; ++j) {
        int idx = (j < c0) ? (i0 + j) : i0;        // clamp to a safe slot (uniform)
        int e = __builtin_amdgcn_readlane(e_l, idx);   // VALU->SGPR broadcast
        int s = __builtin_amdgcn_readlane(s_l, idx);
        xs[j] = *(const float4*)(xl + (size_t)s * 256 + cb);   // independent, in flight
        a0[j] = *(const float4*)(ea + (size_t)e * 8);
        a1[j] = *(const float4*)(ea + (size_t)e * 8 + 4);
      }
      __builtin_amdgcn_s_setprio(1);     // data-ready wave: prefer its VALU burst
      // --- logits for the whole chunk, fully independent across j ---
      float v[4];
#pragma unroll
      for (int j = 0; j < 4; ++j) {
        if (j < c0) {
          float e0 = a0[j].x * w0.x + a0[j].y * w1.x + a0[j].z * w2.x + a0[j].w * w3.x
                   + a1[j].x * w4_.x + a1[j].y * w5.x + a1[j].z * w6.x + a1[j].w * w7.x;
          float e1 = a0[j].x * w0.y + a0[j].y * w1.y + a0[j].z * w2.y + a0[j].w * w3.y
                   + a1[j].x * w4_.y + a1[j].y * w5.y + a1[j].z * w6.y + a1[j].w * w7.y;
          float e2 = a0[j].x * w0.z + a0[j].y * w1.z + a0[j].z * w2.z + a0[j].w * w3.z
                   + a1[j].x * w4_.z + a1[j].y * w5.z + a1[j].z * w6.z + a1[j].w * w7.z;
          float e3 = a0[j].x * w0.w + a0[j].y * w1.w + a0[j].z * w2.w + a0[j].w * w3.w
                   + a1[j].x * w4_.w + a1[j].y * w5.w + a1[j].z * w6.w + a1[j].w * w7.w;
          float m0 = xs[j].x + xd4.x + e0; m0 = (m0 >= 0.f) ? m0 : 0.2f * m0;  // leaky
          float m1 = xs[j].y + xd4.y + e1; m1 = (m1 >= 0.f) ? m1 : 0.2f * m1;
          float m2 = xs[j].z + xd4.z + e2; m2 = (m2 >= 0.f) ? m2 : 0.2f * m2;
          float m3 = xs[j].w + xd4.w + e3; m3 = (m3 >= 0.f) ? m3 : 0.2f * m3;
          float d = at4.x * m0 + at4.y * m1 + at4.z * m2 + at4.w * m3;
          v[j] = row16_sum(d);           // 4 independent DPP chains interleave on VALU
        } else {
          v[j] = -INFINITY;              // pad slot: p=exp(-inf-nm)=0, no contribution
        }
      }
      // --- ONE max + rescale for the whole chunk ---
      float vm = fmaxf(fmaxf(v[0], v[1]), fmaxf(v[2], v[3]));
      float nm = fmaxf(m, vm);
      float scale = __expf(m - nm);      // first chunk: m=-inf -> scale=0
      float p0 = __expf(v[0] - nm), p1 = __expf(v[1] - nm);
      float p2 = __expf(v[2] - nm), p3 = __expf(v[3] - nm);
      ox = ox * scale + ((p0 * xs[0].x + p1 * xs[1].x) + (p2 * xs[2].x + p3 * xs[3].x));
      oy = oy * scale + ((p0 * xs[0].y + p1 * xs[1].y) + (p2 * xs[2].y + p3 * xs[3].y));
      oz = oz * scale + ((p0 * xs[0].z + p1 * xs[1].z) + (p2 * xs[2].z + p3 * xs[3].z));
      ow = ow * scale + ((p0 * xs[0].w + p1 * xs[1].w) + (p2 * xs[2].w + p3 * xs[3].w));
      l = l * scale + ((p0 + p1) + (p2 + p3));
      m = nm;
      __builtin_amdgcn_s_setprio(0);     // back to normal for the next gather wait
    }
    // per-head y = O/den, then 0.25 * head-sum  (deg==0 -> l=0 -> y=0, matches ref)
    float inv = 0.25f / fmaxf(l, 1e-16f);
    float r0 = ox * inv, r1 = oy * inv, r2 = oz * inv, r3 = ow * inv;
    r0 += __shfl_xor(r0, 16, 64); r0 += __shfl_xor(r0, 32, 64);
    r1 += __shfl_xor(r1, 16, 64); r1 += __shfl_xor(r1, 32, 64);
    r2 += __shfl_xor(r2, 16, 64); r2 += __shfl_xor(r2, 32, 64);
    r3 += __shfl_xor(r3, 16, 64); r3 += __shfl_xor(r3, 32, 64);
    float rr0 = fmaxf(r0 + bi4.x, 0.f), rr1 = fmaxf(r1 + bi4.y, 0.f);
    float rr2 = fmaxf(r2 + bi4.z, 0.f), rr3 = fmaxf(r3 + bi4.w, 0.f);
    if (lane < 16) *(float4*)(out + (size_t)n * 64 + cg * 4) = float4{rr0, rr1, rr2, rr3};
    // topk score: s = tanh(h.w / ||w||)
    float dot = rr0 * pw4.x + rr1 * pw4.y + rr2 * pw4.z + rr3 * pw4.w;
    dot += __shfl_xor(dot, 1, 64);
    dot += __shfl_xor(dot, 2, 64);
    dot += __shfl_xor(dot, 4, 64);
    dot += __shfl_xor(dot, 8, 64);
    if (lane == 0) sc[n] = tanhf(dot * isq);
    // rotate pipeline registers
    degc = degn; e_c = e_n; s_c = s_n; xdc = xdn;
  }
}

// stable descending top-k per graph — u64 keys (ford(score)<<32 | ~idx).
// Hybrid bitonic over 2048 elements, 2 elements/thread in registers (measured R6).
// Also zeroes cnt[0, B*k) for the next layer (replaces a hipMemsetAsync).
__global__ __launch_bounds__(1024) void k_topk(const float* __restrict__ s, int n_per,
                                               int k,
                                               int* __restrict__ perm, int* __restrict__ new_id,
                                               int* __restrict__ cnt) {
  __shared__ u64 kv[2048];
  int b = blockIdx.x, t = threadIdx.x;
  int base = b * n_per;
  for (int i = t; i < n_per; i += 1024) new_id[base + i] = -1;
  for (int i = t; i < k; i += 1024) cnt[b * k + i] = 0;   // next layer's CSR counters

  u64 e0, e1;
  {
    u32 sk0 = (t < n_per) ? ford(s[base + t]) : 0u;             // pad key 0: below all
    int i1 = t + 1024;
    u32 sk1 = (i1 < n_per) ? ford(s[base + i1]) : 0u;
    e0 = ((u64)sk0 << 32) | (u32)(0xFFFFFFFFu - (u32)t);        // tie -> lower idx first
    e1 = ((u64)sk1 << 32) | (u32)(0xFFFFFFFFu - (u32)i1);
  }

  for (int kk = 2; kk <= 2048; kk <<= 1) {
    int j = kk >> 1;
    if (j == 1024) {                     // partner of element t is element t+1024: local
      u64 mx = e0 > e1 ? e0 : e1;
      u64 mn = e0 > e1 ? e1 : e0;
      e0 = mx; e1 = mn;
      j >>= 1;
    }
    for (; j >= 64; j >>= 1) {           // cross-wave: LDS exchange
      __syncthreads();                   // prior pass's reads complete before overwrite
      kv[t] = e0; kv[t + 1024] = e1;
      __syncthreads();
      u64 p0 = kv[t ^ j], p1 = kv[(t + 1024) ^ j];
      int i1 = t + 1024;
      bool km0 = (((t  & kk) == 0) == ((t  & j) == 0));
      bool km1 = (((i1 & kk) == 0) == ((i1 & j) == 0));
      e0 = km0 ? (e0 > p0 ? e0 : p0) : (e0 < p0 ? e0 : p0);
      e1 = km1 ? (e1 > p1 ? e1 : p1) : (e1 < p1 ? e1 : p1);
    }
    for (; j >= 1; j >>= 1) {            // intra-wave: shuffle exchange, no barriers
      u64 p0 = shfl_xor_u64(e0, j);
      u64 p1 = shfl_xor_u64(e1, j);
      int i1 = t + 1024;
      bool km0 = (((t  & kk) == 0) == ((t  & j) == 0));
      bool km1 = (((i1 & kk) == 0) == ((i1 & j) == 0));
      e0 = km0 ? (e0 > p0 ? e0 : p0) : (e0 < p0 ? e0 : p0);
      e1 = km1 ? (e1 > p1 ? e1 : p1) : (e1 < p1 ? e1 : p1);
    }
  }

  // element i holds rank i (descending): e0 = rank t, e1 = rank t+1024
  if (t < k) {
    int old0 = (int)(0xFFFFFFFFu - (u32)(e0 & 0xFFFFFFFFu));
    perm[b * k + t] = base + old0;
    new_id[base + old0] = b * k + t;
  }
  int r1 = t + 1024;
  if (r1 < k) {
    int old1 = (int)(0xFFFFFFFFu - (u32)(e1 & 0xFFFFFFFFu));
    perm[b * k + r1] = base + old1;
    new_id[base + old1] = b * k + r1;
  }
}

// fused post-pool: WIDE gather+readout AND edge remap in ONE launch (measured good;
// R10 narrow fusion and R12 spin fusion both regressed — width matters).
// grid: dim3(32, gather_rows [+ REMAP_Y when do_remap]).
__global__ void k_post(const float* __restrict__ hin, const float* __restrict__ s,
                       const int* __restrict__ perm, float* __restrict__ hout,
                       int k, int gather_rows,
                       float* __restrict__ rsum, u32* __restrict__ rmaxI,
                       int* __restrict__ src, int* __restrict__ dst, int* __restrict__ em,
                       const int* __restrict__ new_id, int* __restrict__ cnt,
                       int* __restrict__ csr, int do_remap) {
  __shared__ float ps[256], pm[256];
  int b = blockIdx.x, yy = blockIdx.y, t = threadIdx.x;
  if (yy < gather_rows) {
    int i = yy * 4 + (t >> 6);            // local kept-node index
    int c = t & 63;
    bool valid = i < k;
    float v = 0.f;
    if (valid) {
      int g = perm[b * k + i];
      v = hin[(size_t)g * 64 + c] * s[g];
      hout[((size_t)b * k + i) * 64 + c] = v;
    }
    ps[t] = valid ? v : 0.f;
    pm[t] = valid ? v : -INFINITY;
    __syncthreads();
    if (t < 64) {
      float s4 = ps[t] + ps[t + 64] + ps[t + 128] + ps[t + 192];
      float m4 = fmaxf(fmaxf(pm[t], pm[t + 64]), fmaxf(pm[t + 128], pm[t + 192]));
      atomicAdd(&rsum[b * 64 + t], s4);
      atomicMax(&rmaxI[b * 64 + t], ford(m4));
    }
  } else if (do_remap) {
    int e = ((yy - gather_rows) * 32 + b) * 256 + t;
    if (e < E_TOT) {
      int ns = new_id[src[e]], nd = new_id[dst[e]];
      int mm = em[e] && ns >= 0 && nd >= 0;
      src[e] = mm ? ns : 0;
      dst[e] = mm ? nd : 0;
      em[e] = mm;
      if (mm) {
        int pos = atomicAdd(&cnt[nd], 1);
        if (pos < MAXDEG) csr[nd * MAXDEG + pos] = e;
      }
    }
  }
}

// MLP with readout finalization folded in: reads [rsum|rmaxI] x 3 layers directly
__global__ void k_mlp(const char* __restrict__ rblk,
                      const float* __restrict__ W1, const float* __restrict__ b1,
                      const float* __restrict__ W2, const float* __restrict__ b2,
                      const float* __restrict__ W3, const float* __restrict__ b3,
                      float* __restrict__ out) {
  __shared__ float v0[128], v1[64], v2[64], lgts[16];
  int b = blockIdx.x, t = threadIdx.x;   // 64 threads
  const float* rs0 = (const float*)rblk;
  const u32*   rm0 = (const u32*)(rblk + 32 * 64 * 4);
  const float* rs1 = (const float*)(rblk + 32 * 128 * 4);
  const u32*   rm1 = (const u32*)(rblk + 32 * 128 * 4 + 32 * 64 * 4);
  const float* rs2 = (const float*)(rblk + 2 * 32 * 128 * 4);
  const u32*   rm2 = (const u32*)(rblk + 2 * 32 * 128 * 4 + 32 * 64 * 4);
  v0[t] = rs0[b * 64 + t] / 1268.f + rs1[b * 64 + t] / 1015.f + rs2[b * 64 + t] / 812.f;
  v0[64 + t] = ford_inv(rm0[b * 64 + t]) + ford_inv(rm1[b * 64 + t]) + ford_inv(rm2[b * 64 + t]);
  __syncthreads();
  float a = b1[t];
  for (int i = 0; i < 128; ++i) a += v0[i] * W1[i * 64 + t];
  v1[t] = fmaxf(a, 0.f);
  __syncthreads();
  a = b2[t];
  for (int i = 0; i < 64; ++i) a += v1[i] * W2[i * 64 + t];
  v2[t] = fmaxf(a, 0.f);
  __syncthreads();
  if (t < 16) {
    a = b3[t];
    for (int i = 0; i < 64; ++i) a += v2[i] * W3[i * 16 + t];
    lgts[t] = a;
  }
  __syncthreads();
  if (t == 0) {
    float m = lgts[0];
    for (int j = 1; j < 16; ++j) m = fmaxf(m, lgts[j]);
    float ex[16], sum = 0.f;
    for (int j = 0; j < 16; ++j) { ex[j] = expf(lgts[j] - m); sum += ex[j]; }
    for (int j = 0; j < 16; ++j) out[b * 16 + j] = ex[j] / sum;
  }
}

extern "C" void kernel_launch(void* const* d_in, const int* in_sizes, int n_in,
                              void* d_out, int out_size, void* d_ws, size_t ws_size,
                              hipStream_t stream) {
  (void)in_sizes; (void)n_in; (void)out_size; (void)ws_size;
  const float* x  = (const float*)d_in[0];      // [NMAX, 32] f32
  const float* ea = (const float*)d_in[1];      // [E, 8]     f32
  const int*   ei = (const int*)d_in[2];        // [2, E]

  const float *gWl[3], *gbl[3], *gWr[3], *gbr[3], *gWe[3], *gatt[3], *gb[3], *pw[3];
  for (int l = 0; l < 3; ++l) {
    int p0 = 4 + 7 * l;
    gWl[l]  = (const float*)d_in[p0 + 0];
    gbl[l]  = (const float*)d_in[p0 + 1];
    gWr[l]  = (const float*)d_in[p0 + 2];
    gbr[l]  = (const float*)d_in[p0 + 3];
    gWe[l]  = (const float*)d_in[p0 + 4];
    gatt[l] = (const float*)d_in[p0 + 5];
    gb[l]   = (const float*)d_in[p0 + 6];
    pw[l]   = (const float*)d_in[25 + l];
  }
  const float* fc1W = (const float*)d_in[28];
  const float* fc1b = (const float*)d_in[29];
  const float* fc2W = (const float*)d_in[30];
  const float* fc2b = (const float*)d_in[31];
  const float* fc3W = (const float*)d_in[32];
  const float* fc3b = (const float*)d_in[33];

  // ---- workspace carve. cnt|rblk|csr CONTIGUOUS (all sizes %256==0): ONE memset ----
  char* w = (char*)d_ws;
  size_t off = 0;
  auto alloc = [&](size_t bytes) -> void* {
    void* p = w + off;
    off += (bytes + 255) & ~(size_t)255;
    return p;
  };
  float* hbuf = (float*)alloc((size_t)B_ * 1268 * 64 * 4); // pooled features (max K1)
  float* xl   = (float*)alloc((size_t)NMAX * 256 * 4);     // source transform [N,256]
  float* xr   = (float*)alloc((size_t)NMAX * 256 * 4);     // target transform [N,256]
  float* nacc = (float*)alloc((size_t)NMAX * 64 * 4);      // fused GAT output (pre-pool)
  int*   cnt  = (int*)alloc((size_t)NMAX * 4);             // CSR degree counters
  char*  rblk = (char*)alloc(3 * 32 * 128 * 4);            // per-layer [rsum][rmaxI] x3
  int*   csr  = (int*)alloc((size_t)NMAX * MAXDEG * 4);
  float* sbuf = (float*)alloc((size_t)NMAX * 4);
  int* src    = (int*)alloc((size_t)E_TOT * 4);
  int* dst    = (int*)alloc((size_t)E_TOT * 4);
  int* em     = (int*)alloc((size_t)E_TOT * 4);
  int* new_id = (int*)alloc((size_t)NMAX * 4);
  int* perm   = (int*)alloc((size_t)32 * 1268 * 4);

  // one-time zero of cnt + rblk + csr (csr zero => every slot is an in-bounds edge id
  // forever, enabling k_gat_fused's unconditional csr/srcv prefetch)
  size_t zbytes = (size_t)NMAX * 4 + 3 * 32 * 128 * 4 + (size_t)NMAX * MAXDEG * 4;
  hipMemsetAsync(cnt, 0, zbytes, stream);

  const int Ns[3]    = {50688, 40576, 32480};   // B*N0, B*K1, B*K2 (all %16==0)
  const int npers[3] = {1584, 1268, 1015};
  const int ks[3]    = {1268, 1015, 812};
  const int GAT_BLOCKS = 2048;                  // 8 XCD x 4 graphs x 64 blocks

  for (int l = 0; l < 3; ++l) {
    int N = Ns[l];
    const float* hin = (l == 0) ? x : hbuf;
    float* rsum = (float*)(rblk + l * 32 * 128 * 4);
    u32* rmaxI  = (u32*)(rblk + l * 32 * 128 * 4 + 32 * 64 * 4);
    if (l == 0)
      k_tre<<<TRE_TBLK + TRE_EBLK, 256, 0, stream>>>(hin, gWl[l], gbl[l], gWr[l], gbr[l],
                                                     xl, xr, ei, src, dst, em, cnt, csr);
    else
      k_transform_t<64><<<N / 16, 256, 0, stream>>>(hin, gWl[l], gbl[l], gWr[l], gbr[l], xl, xr);
    k_gat_fused<<<GAT_BLOCKS, 256, 0, stream>>>(src, cnt, csr, ea, gWe[l], gatt[l],
                                                xl, xr, gb[l], pw[l], nacc, sbuf, npers[l]);
    k_topk<<<32, 1024, 0, stream>>>(sbuf, npers[l], ks[l], perm, new_id, cnt);
    int grows = CDIV(ks[l], 4);
    dim3 pgrid(32, grows + (l < 2 ? REMAP_Y : 0));
    k_post<<<pgrid, 256, 0, stream>>>(nacc, sbuf, perm, hbuf, ks[l], grows, rsum, rmaxI,
                                      src, dst, em, new_id, cnt, csr, (l < 2) ? 1 : 0);
  }
  k_mlp<<<32, 64, 0, stream>>>(rblk, fc1W, fc1b, fc2W, fc2b, fc3W, fc3b, (float*)d_out);
}